// Round 17
// baseline (1174.440 us; speedup 1.0000x reference)
//
#include <hip/hip_runtime.h>

#define LSEQ 9216
#define CDIM 128
#define ED   512
#define DI   256
#define NST  16
#define NCH  512
#define CHL  18
#define SEG  32
#define LOG2E 1.44269504f
#define LN2  0.6931471805599453f

#if defined(__has_builtin)
#  if __has_builtin(__builtin_amdgcn_exp2f)
#    define FEXP2(x) __builtin_amdgcn_exp2f(x)
#  endif
#  if __has_builtin(__builtin_amdgcn_logf)
#    define FLOG2(x) __builtin_amdgcn_logf(x)
#  endif
#  if __has_builtin(__builtin_amdgcn_rcpf)
#    define FRCP(x) __builtin_amdgcn_rcpf(x)
#  endif
#endif
#ifndef FEXP2
#  define FEXP2(x) exp2f(x)
#endif
#ifndef FLOG2
#  define FLOG2(x) log2f(x)
#endif
#ifndef FRCP
#  define FRCP(x) (1.f / (x))
#endif

typedef __attribute__((ext_vector_type(8))) short short8v;
typedef __attribute__((ext_vector_type(4))) float float4v;

__device__ __forceinline__ float fsilu(float x) {
  return x * FRCP(1.f + FEXP2(-LOG2E * x));
}
__device__ __forceinline__ float fsoftplus(float x) {
  float sp = FLOG2(1.f + FEXP2(LOG2E * x)) * LN2;
  return (x > 20.f) ? x : sp;
}
__device__ __forceinline__ unsigned short f2bf(float f) {
  union { float f; unsigned u; } v; v.f = f;
  return (unsigned short)((v.u + 0x7FFFu + ((v.u >> 16) & 1u)) >> 16);
}
__device__ __forceinline__ float bf2f(unsigned short u) {
  union { unsigned u; float f; } v; v.u = ((unsigned)u) << 16;
  return v.f;
}
__device__ __forceinline__ int lmap(int p, int mode) {
  if (mode == 0) return p;
  if (mode == 1) return LSEQ - 1 - p;
  return (p & 15) * 576 + (p >> 4);
}

// A2[dir][d][n] = -exp(A_log)*log2(e)
__global__ __launch_bounds__(256) void a2_kernel(
    const float* __restrict__ Af, const float* __restrict__ Ab,
    const float* __restrict__ As, float* __restrict__ A2) {
  int i = blockIdx.x * 256 + threadIdx.x;
  if (i >= 3 * DI * NST) return;
  int dir = i / (DI * NST), j = i % (DI * NST);
  const float* src = (dir == 0) ? Af : ((dir == 1) ? Ab : As);
  A2[i] = -expf(src[j]) * LOG2E;
}

// cast f32 -> bf16 (weights, tiny)
__global__ __launch_bounds__(256) void wcast_kernel(
    const float* __restrict__ src, unsigned short* __restrict__ dst, int n) {
  int i = blockIdx.x * 256 + threadIdx.x;
  if (i < n) dst[i] = f2bf(src[i]);
}

// LayerNorm over C at each (b,l): x (B,C,L) f32 -> xn (B,L,C) bf16
__global__ __launch_bounds__(256) void ln_kernel(
    const float* __restrict__ x, const float* __restrict__ w,
    const float* __restrict__ bb, unsigned short* __restrict__ xn) {
  __shared__ float xt[CDIM][65];
  __shared__ float ps[4][64], pq[4][64];
  __shared__ float mu_s[64], rs_s[64];
  const int b = blockIdx.y, l0 = blockIdx.x * 64, tid = threadIdx.x;
  for (int idx = tid; idx < CDIM * 64; idx += 256) {
    int c = idx >> 6, ll = idx & 63;
    xt[c][ll] = x[((size_t)(b * CDIM + c)) * LSEQ + l0 + ll];
  }
  __syncthreads();
  {
    int ll = tid & 63, grp = tid >> 6;
    float s = 0.f, q = 0.f;
    for (int c = grp * 32; c < grp * 32 + 32; ++c) {
      float v = xt[c][ll]; s += v; q += v * v;
    }
    ps[grp][ll] = s; pq[grp][ll] = q;
  }
  __syncthreads();
  if (tid < 64) {
    float S = ps[0][tid] + ps[1][tid] + ps[2][tid] + ps[3][tid];
    float Q = pq[0][tid] + pq[1][tid] + pq[2][tid] + pq[3][tid];
    float mu = S * (1.f / 128.f);
    float var = Q * (1.f / 128.f) - mu * mu;
    mu_s[tid] = mu;
    rs_s[tid] = rsqrtf(var + 1e-5f);
  }
  __syncthreads();
  for (int idx = tid; idx < 64 * CDIM; idx += 256) {
    int c = idx & 127, ll = idx >> 7;
    float v = (xt[c][ll] - mu_s[ll]) * rs_s[ll] * w[c] + bb[c];
    xn[((size_t)(b * LSEQ + l0 + ll)) * CDIM + c] = f2bf(v);
  }
}

// MFMA GEMM: Out[m,n] = sum_k A[m,k]*Wb[n,k].
template <bool A_BF16, bool OUT_BF16>
__global__ __launch_bounds__(256) void gemm_mfma(
    const void* __restrict__ Ap, const unsigned short* __restrict__ Wb,
    void* __restrict__ Outp, int N, int K, int ldo) {
  __shared__ __align__(16) unsigned short As[64][40];
  __shared__ __align__(16) unsigned short Bs[128][40];
  const int tid = threadIdx.x;
  const int lane = tid & 63, wid = tid >> 6;
  const int wr = wid >> 1, wc = wid & 1;
  const int m0 = blockIdx.x * 64, n0 = blockIdx.y * 128;
  float4v acc[2][4];
#pragma unroll
  for (int s = 0; s < 2; ++s)
#pragma unroll
    for (int t = 0; t < 4; ++t)
#pragma unroll
      for (int r = 0; r < 4; ++r) acc[s][t][r] = 0.f;

  const int srow = tid >> 2, sslot = tid & 3;
  for (int k0 = 0; k0 < K; k0 += 32) {
    if constexpr (A_BF16) {
      const unsigned short* A = (const unsigned short*)Ap;
      *(short8v*)&As[srow][sslot * 8] =
          *(const short8v*)&A[(size_t)(m0 + srow) * K + k0 + sslot * 8];
    } else {
      const float* A = (const float*)Ap;
      const float4* src = (const float4*)&A[(size_t)(m0 + srow) * K + k0 + sslot * 8];
      float4 f0 = src[0], f1 = src[1];
      short8v v;
      v[0] = (short)f2bf(f0.x); v[1] = (short)f2bf(f0.y);
      v[2] = (short)f2bf(f0.z); v[3] = (short)f2bf(f0.w);
      v[4] = (short)f2bf(f1.x); v[5] = (short)f2bf(f1.y);
      v[6] = (short)f2bf(f1.z); v[7] = (short)f2bf(f1.w);
      *(short8v*)&As[srow][sslot * 8] = v;
    }
#pragma unroll
    for (int i = 0; i < 2; ++i) {
      int row = i * 64 + srow;
      int n = n0 + row;
      short8v v;
      if (n < N) {
        v = *(const short8v*)&Wb[(size_t)n * K + k0 + sslot * 8];
      } else {
#pragma unroll
        for (int q = 0; q < 8; ++q) v[q] = 0;
      }
      *(short8v*)&Bs[row][sslot * 8] = v;
    }
    __syncthreads();
    const int kk = (lane >> 4) * 8;
    const int mr = wr * 32 + (lane & 15);
    const int nr = wc * 64 + (lane & 15);
    short8v a_frag[2], b_frag[4];
#pragma unroll
    for (int s = 0; s < 2; ++s)
      a_frag[s] = *(const short8v*)&As[mr + s * 16][kk];
#pragma unroll
    for (int t = 0; t < 4; ++t)
      b_frag[t] = *(const short8v*)&Bs[nr + t * 16][kk];
#pragma unroll
    for (int s = 0; s < 2; ++s)
#pragma unroll
      for (int t = 0; t < 4; ++t)
        acc[s][t] = __builtin_amdgcn_mfma_f32_16x16x32_bf16(
            a_frag[s], b_frag[t], acc[s][t], 0, 0, 0);
    __syncthreads();
  }
  const int rbase = (lane >> 4) * 4;
  const int cbase = lane & 15;
#pragma unroll
  for (int s = 0; s < 2; ++s)
#pragma unroll
    for (int t = 0; t < 4; ++t) {
      int n = n0 + wc * 64 + t * 16 + cbase;
      if (n < N) {
#pragma unroll
        for (int r = 0; r < 4; ++r) {
          int m = m0 + wr * 32 + s * 16 + rbase + r;
          if constexpr (OUT_BF16)
            ((unsigned short*)Outp)[(size_t)m * ldo + n] = f2bf(acc[s][t][r]);
          else
            ((float*)Outp)[(size_t)m * ldo + n] = acc[s][t][r];
        }
      }
    }
}

// Fused out_proj + residual + channel LayerNorm. (verified round-15)
__global__ __launch_bounds__(256) void gemm_out_final(
    const unsigned short* __restrict__ yf, const unsigned short* __restrict__ yb,
    const unsigned short* __restrict__ ys, const unsigned short* __restrict__ Wb,
    const float* __restrict__ x, const float* __restrict__ nmw,
    const float* __restrict__ nmb, float* __restrict__ out) {
  __shared__ __align__(16) unsigned short As[64][40];
  __shared__ __align__(16) unsigned short Bs[128][40];
  __shared__ float yt[64][129];
  __shared__ float ps[4][64], pq[4][64], mu_s[64], rs_s[64];
  const int tid = threadIdx.x;
  const int lane = tid & 63, wid = tid >> 6;
  const int wr = wid >> 1, wc = wid & 1;
  const int m0 = blockIdx.x * 64;
  const int b = blockIdx.x / 144, l0 = (blockIdx.x % 144) * 64;
  float4v acc[2][4];
#pragma unroll
  for (int s = 0; s < 2; ++s)
#pragma unroll
    for (int t = 0; t < 4; ++t)
#pragma unroll
      for (int r = 0; r < 4; ++r) acc[s][t][r] = 0.f;

  const int srow = tid >> 2, sslot = tid & 3;
  for (int k0 = 0; k0 < 256; k0 += 32) {
    {
      size_t base = (size_t)(m0 + srow) * DI + k0 + sslot * 8;
      short8v vf = *(const short8v*)&yf[base];
      short8v vb = *(const short8v*)&yb[base];
      short8v vs = *(const short8v*)&ys[base];
      short8v v;
#pragma unroll
      for (int q = 0; q < 8; ++q) {
        float f = bf2f((unsigned short)vf[q]) + bf2f((unsigned short)vb[q]) +
                  bf2f((unsigned short)vs[q]);
        v[q] = (short)f2bf(f);
      }
      *(short8v*)&As[srow][sslot * 8] = v;
    }
#pragma unroll
    for (int i = 0; i < 2; ++i) {
      int row = i * 64 + srow;
      *(short8v*)&Bs[row][sslot * 8] =
          *(const short8v*)&Wb[(size_t)row * 256 + k0 + sslot * 8];
    }
    __syncthreads();
    const int kk = (lane >> 4) * 8;
    const int mr = wr * 32 + (lane & 15);
    const int nr = wc * 64 + (lane & 15);
    short8v a_frag[2], b_frag[4];
#pragma unroll
    for (int s = 0; s < 2; ++s)
      a_frag[s] = *(const short8v*)&As[mr + s * 16][kk];
#pragma unroll
    for (int t = 0; t < 4; ++t)
      b_frag[t] = *(const short8v*)&Bs[nr + t * 16][kk];
#pragma unroll
    for (int s = 0; s < 2; ++s)
#pragma unroll
      for (int t = 0; t < 4; ++t)
        acc[s][t] = __builtin_amdgcn_mfma_f32_16x16x32_bf16(
            a_frag[s], b_frag[t], acc[s][t], 0, 0, 0);
    __syncthreads();
  }
  const int rbase = (lane >> 4) * 4;
  const int cbase = lane & 15;
#pragma unroll
  for (int s = 0; s < 2; ++s)
#pragma unroll
    for (int t = 0; t < 4; ++t) {
      int cc = wc * 64 + t * 16 + cbase;
#pragma unroll
      for (int r = 0; r < 4; ++r)
        yt[wr * 32 + s * 16 + rbase + r][cc] = acc[s][t][r];
    }
  __syncthreads();
  for (int idx = tid; idx < CDIM * 64; idx += 256) {
    int c = idx >> 6, ll = idx & 63;
    yt[ll][c] += x[((size_t)(b * CDIM + c)) * LSEQ + l0 + ll];
  }
  __syncthreads();
  {
    int ll = tid & 63, grp = tid >> 6;
    float s = 0.f, q = 0.f;
    for (int c = grp * 32; c < grp * 32 + 32; ++c) {
      float v = yt[ll][c]; s += v; q += v * v;
    }
    ps[grp][ll] = s; pq[grp][ll] = q;
  }
  __syncthreads();
  if (tid < 64) {
    float S = ps[0][tid] + ps[1][tid] + ps[2][tid] + ps[3][tid];
    float Q = pq[0][tid] + pq[1][tid] + pq[2][tid] + pq[3][tid];
    float mu = S * (1.f / 128.f);
    float var = Q * (1.f / 128.f) - mu * mu;
    mu_s[tid] = mu;
    rs_s[tid] = rsqrtf(var + 1e-6f);
  }
  __syncthreads();
  for (int idx = tid; idx < CDIM * 64; idx += 256) {
    int c = idx >> 6, ll = idx & 63;
    float v = yt[ll][c];
    out[((size_t)(b * CDIM + c)) * LSEQ + l0 + ll] =
        v + nmw[c] * (v - mu_s[ll]) * rs_s[ll] + nmb[c];
  }
}

// depthwise causal conv4 + bias + silu; xz bf16 in, xc bf16 out
template <int MODE>
__global__ __launch_bounds__(256) void conv_kernel(
    const unsigned short* __restrict__ xz, const float* __restrict__ cw,
    const float* __restrict__ cb, unsigned short* __restrict__ xc) {
  __shared__ float xs[67][64];
  const int p0 = blockIdx.x * 64, d0 = blockIdx.y * 64, b = blockIdx.z;
  const int tid = threadIdx.x;
  for (int idx = tid; idx < 67 * 32; idx += 256) {
    int pp = idx >> 5, dd2 = idx & 31;
    int q = p0 + pp - 3;
    float v0 = 0.f, v1 = 0.f;
    if (q >= 0) {
      int l = lmap(q, MODE);
      unsigned uu = *(const unsigned*)&xz[((size_t)b * LSEQ + l) * ED + d0 + dd2 * 2];
      union { unsigned u; float f; } a, c;
      a.u = (uu & 0xFFFFu) << 16;
      c.u = uu & 0xFFFF0000u;
      v0 = a.f; v1 = c.f;
    }
    xs[pp][dd2 * 2] = v0;
    xs[pp][dd2 * 2 + 1] = v1;
  }
  __syncthreads();
  const int dd = tid & 63, pg = tid >> 6;
  const int d = d0 + dd;
  const float w0 = cw[d * 4 + 0], w1 = cw[d * 4 + 1];
  const float w2 = cw[d * 4 + 2], w3 = cw[d * 4 + 3];
  const float bias = cb[d];
  for (int pp = pg * 16; pp < pg * 16 + 16; ++pp) {
    float acc = bias + w0 * xs[pp][dd] + w1 * xs[pp + 1][dd] +
                w2 * xs[pp + 2][dd] + w3 * xs[pp + 3][dd];
    xc[((size_t)b * LSEQ + p0 + pp) * DI + d] = f2bf(fsilu(acc));
  }
}

// phase 1 (state-split): lane pair shares channel d; lane owns 8 states.
// NEW: caches dtv (bf16) for p3 to reuse (even lane stores).
__global__ __launch_bounds__(256, 8) void scan_p1(
    const unsigned short* __restrict__ xc, const float* __restrict__ xdbl,
    const float* __restrict__ A2, const float* __restrict__ dtw,
    const float* __restrict__ dtbias, unsigned short* __restrict__ hout,
    float* __restrict__ dts, unsigned short* __restrict__ dtv_buf) {
  __shared__ __align__(16) float Xl[CHL][24];
  const int c = blockIdx.x, b = blockIdx.y;
  const int d = (blockIdx.z << 7) + (threadIdx.x >> 1);
  const int s = threadIdx.x & 1;
  const int p0 = c * CHL;
  for (int idx = threadIdx.x; idx < CHL * 24; idx += 256) {
    int pr = idx / 24, r = idx % 24;
    Xl[pr][r] = xdbl[((size_t)b * LSEQ + p0 + pr) * 40 + r];
  }
  float a2[8], h[8], dw[8];
  {
    const float4* A2v = (const float4*)(A2 + d * NST + s * 8);
    float4 t0 = A2v[0], t1 = A2v[1];
    a2[0] = t0.x; a2[1] = t0.y; a2[2] = t0.z; a2[3] = t0.w;
    a2[4] = t1.x; a2[5] = t1.y; a2[6] = t1.z; a2[7] = t1.w;
    const float4* Wv = (const float4*)(dtw + d * 8);
    float4 w0 = Wv[0], w1 = Wv[1];
    dw[0] = w0.x; dw[1] = w0.y; dw[2] = w0.z; dw[3] = w0.w;
    dw[4] = w1.x; dw[5] = w1.y; dw[6] = w1.z; dw[7] = w1.w;
  }
#pragma unroll
  for (int n = 0; n < 8; ++n) h[n] = 0.f;
  const float dbias = dtbias[d];
  float dtsum = 0.f;
  const unsigned short* up = xc + ((size_t)b * LSEQ + p0) * DI + d;
  unsigned short* dtp = dtv_buf + ((size_t)b * LSEQ + p0) * DI + d;
  __syncthreads();
  for (int pr = 0; pr < CHL; ++pr) {
    const float u = bf2f(*up); up += DI;
    const float4* Xr = (const float4*)Xl[pr];
    float4 x0 = Xr[0], x1 = Xr[1];
    float raw = dbias;
    raw = fmaf(dw[0], x0.x, raw); raw = fmaf(dw[1], x0.y, raw);
    raw = fmaf(dw[2], x0.z, raw); raw = fmaf(dw[3], x0.w, raw);
    raw = fmaf(dw[4], x1.x, raw); raw = fmaf(dw[5], x1.y, raw);
    raw = fmaf(dw[6], x1.z, raw); raw = fmaf(dw[7], x1.w, raw);
    const float dtv = fsoftplus(raw);
    if (s == 0) *dtp = f2bf(dtv);
    dtp += DI;
    const float dtu = dtv * u;
    dtsum += dtv;
    float4 b0 = Xr[2 + 2 * s], b1 = Xr[3 + 2 * s];
    const float Bv[8] = {b0.x, b0.y, b0.z, b0.w, b1.x, b1.y, b1.z, b1.w};
#pragma unroll
    for (int n = 0; n < 8; ++n) {
      float a = FEXP2(dtv * a2[n]);
      h[n] = fmaf(h[n], a, dtu * Bv[n]);
    }
  }
  unsigned short* hb = hout + (((size_t)c * 4 + b) * DI + d) * NST + s * 8;
  uint4 pk;
  pk.x = ((unsigned)f2bf(h[1]) << 16) | f2bf(h[0]);
  pk.y = ((unsigned)f2bf(h[3]) << 16) | f2bf(h[2]);
  pk.z = ((unsigned)f2bf(h[5]) << 16) | f2bf(h[4]);
  pk.w = ((unsigned)f2bf(h[7]) << 16) | f2bf(h[6]);
  *(uint4*)hb = pk;
  if (s == 0) dts[((size_t)c * 4 + b) * DI + d] = dtsum;
}

// phase 2a: local scan within segments of SEG chunks (16 segments).
__global__ __launch_bounds__(256) void scan_p2a(
    unsigned short* __restrict__ hbuf, const float* __restrict__ dts,
    const float* __restrict__ A2, float* __restrict__ cumdts,
    float* __restrict__ segH, float* __restrict__ segdts) {
  const int s = blockIdx.x >> 4;
  const int rest = ((blockIdx.x & 15) << 8) + threadIdx.x;
  const int b = blockIdx.y;
  const int d = rest >> 4;
  const float a2 = A2[rest];
  const int c0 = s * SEG;
  float h = 0.f, cum = 0.f;
  float nh = bf2f(hbuf[((size_t)(c0 * 4 + b) << 12) + rest]);
  float nd = dts[(size_t)(c0 * 4 + b) * DI + d];
  for (int c = c0; c < c0 + SEG; ++c) {
    const float tmp = nh, dcur = nd;
    if (c + 1 < c0 + SEG) {
      nh = bf2f(hbuf[((size_t)((c + 1) * 4 + b) << 12) + rest]);
      nd = dts[(size_t)((c + 1) * 4 + b) * DI + d];
    }
    if ((rest & 15) == 0) cumdts[(size_t)(c * 4 + b) * DI + d] = cum;
    cum += dcur;
    hbuf[((size_t)(c * 4 + b) << 12) + rest] = f2bf(h);
    h = fmaf(FEXP2(dcur * a2), h, tmp);
  }
  segH[((size_t)(s * 4 + b) << 12) + rest] = h;
  if ((rest & 15) == 0) segdts[(size_t)(s * 4 + b) * DI + d] = cum;
}

// phase 2b: serial combine across the 16 segments (f32)
__global__ __launch_bounds__(256) void scan_p2b(
    const float* __restrict__ segH, const float* __restrict__ segdts,
    const float* __restrict__ A2, float* __restrict__ segcarry) {
  const int g = blockIdx.x * 256 + threadIdx.x;
  const int b = g >> 12;
  const int rest = g & 4095;
  const int d = rest >> 4;
  const float a2 = A2[rest];
  float carry = 0.f;
#pragma unroll
  for (int s = 0; s < 16; ++s) {
    segcarry[((size_t)(s * 4 + b) << 12) + rest] = carry;
    const float decay = FEXP2(segdts[(size_t)(s * 4 + b) * DI + d] * a2);
    carry = fmaf(decay, carry, segH[((size_t)(s * 4 + b) << 12) + rest]);
  }
}

// phase 3 (state-split + cached dt): loads dtv from p1's cache; no dt-dot.
// LDS row holds only B|C (32 floats). Lane s takes B quads 2s,2s+1 and
// C quads 4+2s,5+2s.
template <int MODE>
__global__ __launch_bounds__(256, 8) void scan_p3(
    const unsigned short* __restrict__ xc, const float* __restrict__ xdbl,
    const unsigned short* __restrict__ xz, const float* __restrict__ A2,
    const unsigned short* __restrict__ dtv_buf,
    const unsigned short* __restrict__ hinit, const float* __restrict__ cumdts,
    const float* __restrict__ segcarry, const float* __restrict__ Dp,
    unsigned short* __restrict__ ybuf) {
  __shared__ __align__(16) float Xl[CHL][32];
  const int c = blockIdx.x, b = blockIdx.y;
  const int d = (blockIdx.z << 7) + (threadIdx.x >> 1);
  const int s = threadIdx.x & 1;
  const int p0 = c * CHL;
  for (int idx = threadIdx.x; idx < CHL * 32; idx += 256) {
    int pr = idx >> 5, r = idx & 31;
    Xl[pr][r] = xdbl[((size_t)b * LSEQ + p0 + pr) * 40 + 8 + r];
  }
  float a2[8], h[8];
  {
    const float4* A2v = (const float4*)(A2 + d * NST + s * 8);
    float4 t0 = A2v[0], t1 = A2v[1];
    a2[0] = t0.x; a2[1] = t0.y; a2[2] = t0.z; a2[3] = t0.w;
    a2[4] = t1.x; a2[5] = t1.y; a2[6] = t1.z; a2[7] = t1.w;
    const uint4* Hv = (const uint4*)(hinit + (((size_t)c * 4 + b) * DI + d) * NST + s * 8);
    uint4 pa = Hv[0];
    const unsigned pw[4] = {pa.x, pa.y, pa.z, pa.w};
#pragma unroll
    for (int j = 0; j < 4; ++j) {
      union { unsigned u; float f; } lo, hi;
      lo.u = (pw[j] & 0xFFFFu) << 16;
      hi.u = pw[j] & 0xFFFF0000u;
      h[2 * j] = lo.f; h[2 * j + 1] = hi.f;
    }
    const float cum = cumdts[((size_t)c * 4 + b) * DI + d];
    const float4* SC = (const float4*)(segcarry +
        (((size_t)(c / SEG) * 4 + b) << 12) + d * NST + s * 8);
    float4 sc0 = SC[0], sc1 = SC[1];
    const float scv[8] = {sc0.x, sc0.y, sc0.z, sc0.w, sc1.x, sc1.y, sc1.z, sc1.w};
#pragma unroll
    for (int n = 0; n < 8; ++n)
      h[n] = fmaf(FEXP2(a2[n] * cum), scv[n], h[n]);
  }
  const float Dv = Dp[d];

  const unsigned short* up = xc + ((size_t)b * LSEQ + p0) * DI + d;
  const unsigned short* dtp = dtv_buf + ((size_t)b * LSEQ + p0) * DI + d;
  const unsigned short* zp;
  unsigned short* op;
  ptrdiff_t zstride, ostride;
  if (MODE == 0) {
    zp = xz + ((size_t)b * LSEQ + p0) * ED + DI + d;              zstride = ED;
    op = ybuf + ((size_t)b * LSEQ + p0) * DI + d;                 ostride = DI;
  } else if (MODE == 1) {
    zp = xz + ((size_t)b * LSEQ + (LSEQ - 1 - p0)) * ED + DI + d; zstride = -(ptrdiff_t)ED;
    op = ybuf + ((size_t)b * LSEQ + (LSEQ - 1 - p0)) * DI + d;    ostride = -(ptrdiff_t)DI;
  } else {
    zp = nullptr; zstride = 0;
    const int lo0 = (p0 % 576) * 16 + p0 / 576;
    op = ybuf + ((size_t)b * LSEQ + lo0) * DI + d;                ostride = 16 * DI;
  }
  __syncthreads();
  for (int pr = 0; pr < CHL; ++pr) {
    const float u = bf2f(*up); up += DI;
    const float dtv = bf2f(*dtp); dtp += DI;
    const float dtu = dtv * u;
    const float4* Xr = (const float4*)Xl[pr];
    float4 b0 = Xr[0 + 2 * s], b1 = Xr[1 + 2 * s];
    float4 c0 = Xr[4 + 2 * s], c1 = Xr[5 + 2 * s];
    const float Bv[8] = {b0.x, b0.y, b0.z, b0.w, b1.x, b1.y, b1.z, b1.w};
    const float Cv[8] = {c0.x, c0.y, c0.z, c0.w, c1.x, c1.y, c1.z, c1.w};
    float y = (s == 0) ? Dv * u : 0.f;
#pragma unroll
    for (int n = 0; n < 8; ++n) {
      float a = FEXP2(dtv * a2[n]);
      h[n] = fmaf(h[n], a, dtu * Bv[n]);
      y = fmaf(h[n], Cv[n], y);
    }
    y += __shfl_xor(y, 1);
    if (s == 0) {
      float z;
      if (MODE == 2) {
        const int p = p0 + pr;
        const int lz = (p & 15) * 576 + (p >> 4);
        z = bf2f(xz[((size_t)b * LSEQ + lz) * ED + DI + d]);
      } else {
        z = bf2f(*zp);
      }
      *op = f2bf(y * fsilu(z));
    }
    if (MODE != 2) zp += zstride;
    op += ostride;
  }
}

extern "C" void kernel_launch(void* const* d_in, const int* in_sizes, int n_in,
                              void* d_out, int out_size, void* d_ws, size_t ws_size,
                              hipStream_t stream) {
  (void)in_sizes; (void)n_in; (void)out_size;
  const float* x         = (const float*)d_in[0];
  const float* ln_w      = (const float*)d_in[1];
  const float* ln_b      = (const float*)d_in[2];
  const float* in_proj_w = (const float*)d_in[3];
  const float* out_projw = (const float*)d_in[4];
  const float* conv_w[3] = {(const float*)d_in[5],  (const float*)d_in[12], (const float*)d_in[19]};
  const float* conv_b[3] = {(const float*)d_in[6],  (const float*)d_in[13], (const float*)d_in[20]};
  const float* xproj[3]  = {(const float*)d_in[7],  (const float*)d_in[14], (const float*)d_in[21]};
  const float* dtw[3]    = {(const float*)d_in[8],  (const float*)d_in[15], (const float*)d_in[22]};
  const float* dtb[3]    = {(const float*)d_in[9],  (const float*)d_in[16], (const float*)d_in[23]};
  const float* alog[3]   = {(const float*)d_in[10], (const float*)d_in[17], (const float*)d_in[24]};
  const float* Dvec[3]   = {(const float*)d_in[11], (const float*)d_in[18], (const float*)d_in[25]};
  const float* nm_w      = (const float*)d_in[26];
  const float* nm_b      = (const float*)d_in[27];

  float* ws = (float*)d_ws;
  unsigned short* xn_us   = (unsigned short*)(ws);             // [0, 2359296)
  unsigned short* xz_us   = (unsigned short*)(ws + 2359296);   // [2359296, 11796480)
  unsigned short* xc_us   = (unsigned short*)(ws + 11796480);  // [11796480, 16515072)
  float* xdbl   = ws + 16515072;   // [16515072, 17989632)
  unsigned short* yf_us   = (unsigned short*)(ws + 17989632);  // [17989632, 22708224)
  unsigned short* yb_us   = (unsigned short*)(ws + 22708224);  // [22708224, 27426816)
  unsigned short* ys_us   = (unsigned short*)(ws + 27426816);  // [27426816, 32145408)
  float* A2     = ws + 32145408;   // [32145408, 32157696)
  unsigned short* wb = (unsigned short*)(ws + 32157696);       // [32157696, 32223232)
  unsigned short* hout_us = (unsigned short*)(ws + 32223232);  // [32223232, 36417536)
  float* dts      = ws + 36417536; // [36417536, 36941824)
  float* cumdts   = ws + 36941824; // [36941824, 37466112)
  float* segH     = ws + 37466112; // [37466112, 37728256)
  float* segdts   = ws + 37728256; // [37728256, 37744640)
  float* segcarry = ws + 37744640; // [37744640, 38006784)
  unsigned short* dtv_us = (unsigned short*)(ws + 38006784);   // [38006784, 42725376)
  if (ws_size < (size_t)42725376 * sizeof(float)) return;

  unsigned short* wb_in  = wb;
  unsigned short* wb_xp0 = wb + 65536;
  unsigned short* wb_xp1 = wb + 75776;
  unsigned short* wb_xp2 = wb + 86016;
  unsigned short* wb_out = wb + 96256;
  unsigned short* wb_xp[3] = {wb_xp0, wb_xp1, wb_xp2};
  unsigned short* ybuf[3] = {yf_us, yb_us, ys_us};

  a2_kernel<<<48, 256, 0, stream>>>(alog[0], alog[1], alog[2], A2);
  wcast_kernel<<<256, 256, 0, stream>>>(in_proj_w, wb_in, 65536);
  wcast_kernel<<<40, 256, 0, stream>>>(xproj[0], wb_xp0, 10240);
  wcast_kernel<<<40, 256, 0, stream>>>(xproj[1], wb_xp1, 10240);
  wcast_kernel<<<40, 256, 0, stream>>>(xproj[2], wb_xp2, 10240);
  wcast_kernel<<<128, 256, 0, stream>>>(out_projw, wb_out, 32768);

  ln_kernel<<<dim3(LSEQ / 64, 4), 256, 0, stream>>>(x, ln_w, ln_b, xn_us);
  gemm_mfma<true, true><<<dim3(576, 4), 256, 0, stream>>>(xn_us, wb_in, xz_us, 512, 128, 512);

  for (int dir = 0; dir < 3; ++dir) {
    if (dir == 0)
      conv_kernel<0><<<dim3(LSEQ / 64, 4, 4), 256, 0, stream>>>(xz_us, conv_w[0], conv_b[0], xc_us);
    else if (dir == 1)
      conv_kernel<1><<<dim3(LSEQ / 64, 4, 4), 256, 0, stream>>>(xz_us, conv_w[1], conv_b[1], xc_us);
    else
      conv_kernel<2><<<dim3(LSEQ / 64, 4, 4), 256, 0, stream>>>(xz_us, conv_w[2], conv_b[2], xc_us);

    gemm_mfma<true, false><<<dim3(576, 1), 256, 0, stream>>>(xc_us, wb_xp[dir], xdbl, 40, 256, 40);

    const float* A2d = A2 + dir * 4096;
    dim3 sg(NCH, 4, 2);  // state-split: z picks channel half
    scan_p1<<<sg, 256, 0, stream>>>(xc_us, xdbl, A2d, dtw[dir], dtb[dir], hout_us, dts, dtv_us);
    scan_p2a<<<dim3(256, 4), 256, 0, stream>>>(hout_us, dts, A2d, cumdts, segH, segdts);
    scan_p2b<<<64, 256, 0, stream>>>(segH, segdts, A2d, segcarry);

    if (dir == 0)
      scan_p3<0><<<sg, 256, 0, stream>>>(xc_us, xdbl, xz_us, A2d, dtv_us,
                                         hout_us, cumdts, segcarry, Dvec[0], ybuf[0]);
    else if (dir == 1)
      scan_p3<1><<<sg, 256, 0, stream>>>(xc_us, xdbl, xz_us, A2d, dtv_us,
                                         hout_us, cumdts, segcarry, Dvec[1], ybuf[1]);
    else
      scan_p3<2><<<sg, 256, 0, stream>>>(xc_us, xdbl, xz_us, A2d, dtv_us,
                                         hout_us, cumdts, segcarry, Dvec[2], ybuf[2]);
  }
  gemm_out_final<<<576, 256, 0, stream>>>(yf_us, yb_us, ys_us, wb_out, x,
                                          nm_w, nm_b, (float*)d_out);
}

// Round 18
// 636.994 us; speedup vs baseline: 1.8437x; 1.8437x over previous
//
#include <hip/hip_runtime.h>

#define LSEQ 9216
#define CDIM 128
#define ED   512
#define DI   256
#define NST  16
#define NCH  512
#define CHL  18
#define SEG  32
#define LOG2E 1.44269504f
#define LN2  0.6931471805599453f

#if defined(__has_builtin)
#  if __has_builtin(__builtin_amdgcn_exp2f)
#    define FEXP2(x) __builtin_amdgcn_exp2f(x)
#  endif
#  if __has_builtin(__builtin_amdgcn_logf)
#    define FLOG2(x) __builtin_amdgcn_logf(x)
#  endif
#  if __has_builtin(__builtin_amdgcn_rcpf)
#    define FRCP(x) __builtin_amdgcn_rcpf(x)
#  endif
#endif
#ifndef FEXP2
#  define FEXP2(x) exp2f(x)
#endif
#ifndef FLOG2
#  define FLOG2(x) log2f(x)
#endif
#ifndef FRCP
#  define FRCP(x) (1.f / (x))
#endif

typedef __attribute__((ext_vector_type(8))) short short8v;
typedef __attribute__((ext_vector_type(4))) float float4v;

__device__ __forceinline__ float fsilu(float x) {
  return x * FRCP(1.f + FEXP2(-LOG2E * x));
}
__device__ __forceinline__ float fsoftplus(float x) {
  float sp = FLOG2(1.f + FEXP2(LOG2E * x)) * LN2;
  return (x > 20.f) ? x : sp;
}
__device__ __forceinline__ unsigned short f2bf(float f) {
  union { float f; unsigned u; } v; v.f = f;
  return (unsigned short)((v.u + 0x7FFFu + ((v.u >> 16) & 1u)) >> 16);
}
__device__ __forceinline__ float bf2f(unsigned short u) {
  union { unsigned u; float f; } v; v.u = ((unsigned)u) << 16;
  return v.f;
}
__device__ __forceinline__ int lmap(int p, int mode) {
  if (mode == 0) return p;
  if (mode == 1) return LSEQ - 1 - p;
  return (p & 15) * 576 + (p >> 4);
}

// A2[dir][d][n] = -exp(A_log)*log2(e)
__global__ __launch_bounds__(256) void a2_kernel(
    const float* __restrict__ Af, const float* __restrict__ Ab,
    const float* __restrict__ As, float* __restrict__ A2) {
  int i = blockIdx.x * 256 + threadIdx.x;
  if (i >= 3 * DI * NST) return;
  int dir = i / (DI * NST), j = i % (DI * NST);
  const float* src = (dir == 0) ? Af : ((dir == 1) ? Ab : As);
  A2[i] = -expf(src[j]) * LOG2E;
}

// cast f32 -> bf16 (weights, tiny)
__global__ __launch_bounds__(256) void wcast_kernel(
    const float* __restrict__ src, unsigned short* __restrict__ dst, int n) {
  int i = blockIdx.x * 256 + threadIdx.x;
  if (i < n) dst[i] = f2bf(src[i]);
}

// LayerNorm over C at each (b,l): x (B,C,L) f32 -> xn (B,L,C) bf16
__global__ __launch_bounds__(256) void ln_kernel(
    const float* __restrict__ x, const float* __restrict__ w,
    const float* __restrict__ bb, unsigned short* __restrict__ xn) {
  __shared__ float xt[CDIM][65];
  __shared__ float ps[4][64], pq[4][64];
  __shared__ float mu_s[64], rs_s[64];
  const int b = blockIdx.y, l0 = blockIdx.x * 64, tid = threadIdx.x;
  for (int idx = tid; idx < CDIM * 64; idx += 256) {
    int c = idx >> 6, ll = idx & 63;
    xt[c][ll] = x[((size_t)(b * CDIM + c)) * LSEQ + l0 + ll];
  }
  __syncthreads();
  {
    int ll = tid & 63, grp = tid >> 6;
    float s = 0.f, q = 0.f;
    for (int c = grp * 32; c < grp * 32 + 32; ++c) {
      float v = xt[c][ll]; s += v; q += v * v;
    }
    ps[grp][ll] = s; pq[grp][ll] = q;
  }
  __syncthreads();
  if (tid < 64) {
    float S = ps[0][tid] + ps[1][tid] + ps[2][tid] + ps[3][tid];
    float Q = pq[0][tid] + pq[1][tid] + pq[2][tid] + pq[3][tid];
    float mu = S * (1.f / 128.f);
    float var = Q * (1.f / 128.f) - mu * mu;
    mu_s[tid] = mu;
    rs_s[tid] = rsqrtf(var + 1e-5f);
  }
  __syncthreads();
  for (int idx = tid; idx < 64 * CDIM; idx += 256) {
    int c = idx & 127, ll = idx >> 7;
    float v = (xt[c][ll] - mu_s[ll]) * rs_s[ll] * w[c] + bb[c];
    xn[((size_t)(b * LSEQ + l0 + ll)) * CDIM + c] = f2bf(v);
  }
}

// MFMA GEMM: Out[m,n] = sum_k A[m,k]*Wb[n,k].
template <bool A_BF16, bool OUT_BF16>
__global__ __launch_bounds__(256) void gemm_mfma(
    const void* __restrict__ Ap, const unsigned short* __restrict__ Wb,
    void* __restrict__ Outp, int N, int K, int ldo) {
  __shared__ __align__(16) unsigned short As[64][40];
  __shared__ __align__(16) unsigned short Bs[128][40];
  const int tid = threadIdx.x;
  const int lane = tid & 63, wid = tid >> 6;
  const int wr = wid >> 1, wc = wid & 1;
  const int m0 = blockIdx.x * 64, n0 = blockIdx.y * 128;
  float4v acc[2][4];
#pragma unroll
  for (int s = 0; s < 2; ++s)
#pragma unroll
    for (int t = 0; t < 4; ++t)
#pragma unroll
      for (int r = 0; r < 4; ++r) acc[s][t][r] = 0.f;

  const int srow = tid >> 2, sslot = tid & 3;
  for (int k0 = 0; k0 < K; k0 += 32) {
    if constexpr (A_BF16) {
      const unsigned short* A = (const unsigned short*)Ap;
      *(short8v*)&As[srow][sslot * 8] =
          *(const short8v*)&A[(size_t)(m0 + srow) * K + k0 + sslot * 8];
    } else {
      const float* A = (const float*)Ap;
      const float4* src = (const float4*)&A[(size_t)(m0 + srow) * K + k0 + sslot * 8];
      float4 f0 = src[0], f1 = src[1];
      short8v v;
      v[0] = (short)f2bf(f0.x); v[1] = (short)f2bf(f0.y);
      v[2] = (short)f2bf(f0.z); v[3] = (short)f2bf(f0.w);
      v[4] = (short)f2bf(f1.x); v[5] = (short)f2bf(f1.y);
      v[6] = (short)f2bf(f1.z); v[7] = (short)f2bf(f1.w);
      *(short8v*)&As[srow][sslot * 8] = v;
    }
#pragma unroll
    for (int i = 0; i < 2; ++i) {
      int row = i * 64 + srow;
      int n = n0 + row;
      short8v v;
      if (n < N) {
        v = *(const short8v*)&Wb[(size_t)n * K + k0 + sslot * 8];
      } else {
#pragma unroll
        for (int q = 0; q < 8; ++q) v[q] = 0;
      }
      *(short8v*)&Bs[row][sslot * 8] = v;
    }
    __syncthreads();
    const int kk = (lane >> 4) * 8;
    const int mr = wr * 32 + (lane & 15);
    const int nr = wc * 64 + (lane & 15);
    short8v a_frag[2], b_frag[4];
#pragma unroll
    for (int s = 0; s < 2; ++s)
      a_frag[s] = *(const short8v*)&As[mr + s * 16][kk];
#pragma unroll
    for (int t = 0; t < 4; ++t)
      b_frag[t] = *(const short8v*)&Bs[nr + t * 16][kk];
#pragma unroll
    for (int s = 0; s < 2; ++s)
#pragma unroll
      for (int t = 0; t < 4; ++t)
        acc[s][t] = __builtin_amdgcn_mfma_f32_16x16x32_bf16(
            a_frag[s], b_frag[t], acc[s][t], 0, 0, 0);
    __syncthreads();
  }
  const int rbase = (lane >> 4) * 4;
  const int cbase = lane & 15;
#pragma unroll
  for (int s = 0; s < 2; ++s)
#pragma unroll
    for (int t = 0; t < 4; ++t) {
      int n = n0 + wc * 64 + t * 16 + cbase;
      if (n < N) {
#pragma unroll
        for (int r = 0; r < 4; ++r) {
          int m = m0 + wr * 32 + s * 16 + rbase + r;
          if constexpr (OUT_BF16)
            ((unsigned short*)Outp)[(size_t)m * ldo + n] = f2bf(acc[s][t][r]);
          else
            ((float*)Outp)[(size_t)m * ldo + n] = acc[s][t][r];
        }
      }
    }
}

// Fused out_proj + residual + channel LayerNorm. (verified round-15)
__global__ __launch_bounds__(256) void gemm_out_final(
    const unsigned short* __restrict__ yf, const unsigned short* __restrict__ yb,
    const unsigned short* __restrict__ ys, const unsigned short* __restrict__ Wb,
    const float* __restrict__ x, const float* __restrict__ nmw,
    const float* __restrict__ nmb, float* __restrict__ out) {
  __shared__ __align__(16) unsigned short As[64][40];
  __shared__ __align__(16) unsigned short Bs[128][40];
  __shared__ float yt[64][129];
  __shared__ float ps[4][64], pq[4][64], mu_s[64], rs_s[64];
  const int tid = threadIdx.x;
  const int lane = tid & 63, wid = tid >> 6;
  const int wr = wid >> 1, wc = wid & 1;
  const int m0 = blockIdx.x * 64;
  const int b = blockIdx.x / 144, l0 = (blockIdx.x % 144) * 64;
  float4v acc[2][4];
#pragma unroll
  for (int s = 0; s < 2; ++s)
#pragma unroll
    for (int t = 0; t < 4; ++t)
#pragma unroll
      for (int r = 0; r < 4; ++r) acc[s][t][r] = 0.f;

  const int srow = tid >> 2, sslot = tid & 3;
  for (int k0 = 0; k0 < 256; k0 += 32) {
    {
      size_t base = (size_t)(m0 + srow) * DI + k0 + sslot * 8;
      short8v vf = *(const short8v*)&yf[base];
      short8v vb = *(const short8v*)&yb[base];
      short8v vs = *(const short8v*)&ys[base];
      short8v v;
#pragma unroll
      for (int q = 0; q < 8; ++q) {
        float f = bf2f((unsigned short)vf[q]) + bf2f((unsigned short)vb[q]) +
                  bf2f((unsigned short)vs[q]);
        v[q] = (short)f2bf(f);
      }
      *(short8v*)&As[srow][sslot * 8] = v;
    }
#pragma unroll
    for (int i = 0; i < 2; ++i) {
      int row = i * 64 + srow;
      *(short8v*)&Bs[row][sslot * 8] =
          *(const short8v*)&Wb[(size_t)row * 256 + k0 + sslot * 8];
    }
    __syncthreads();
    const int kk = (lane >> 4) * 8;
    const int mr = wr * 32 + (lane & 15);
    const int nr = wc * 64 + (lane & 15);
    short8v a_frag[2], b_frag[4];
#pragma unroll
    for (int s = 0; s < 2; ++s)
      a_frag[s] = *(const short8v*)&As[mr + s * 16][kk];
#pragma unroll
    for (int t = 0; t < 4; ++t)
      b_frag[t] = *(const short8v*)&Bs[nr + t * 16][kk];
#pragma unroll
    for (int s = 0; s < 2; ++s)
#pragma unroll
      for (int t = 0; t < 4; ++t)
        acc[s][t] = __builtin_amdgcn_mfma_f32_16x16x32_bf16(
            a_frag[s], b_frag[t], acc[s][t], 0, 0, 0);
    __syncthreads();
  }
  const int rbase = (lane >> 4) * 4;
  const int cbase = lane & 15;
#pragma unroll
  for (int s = 0; s < 2; ++s)
#pragma unroll
    for (int t = 0; t < 4; ++t) {
      int cc = wc * 64 + t * 16 + cbase;
#pragma unroll
      for (int r = 0; r < 4; ++r)
        yt[wr * 32 + s * 16 + rbase + r][cc] = acc[s][t][r];
    }
  __syncthreads();
  for (int idx = tid; idx < CDIM * 64; idx += 256) {
    int c = idx >> 6, ll = idx & 63;
    yt[ll][c] += x[((size_t)(b * CDIM + c)) * LSEQ + l0 + ll];
  }
  __syncthreads();
  {
    int ll = tid & 63, grp = tid >> 6;
    float s = 0.f, q = 0.f;
    for (int c = grp * 32; c < grp * 32 + 32; ++c) {
      float v = yt[ll][c]; s += v; q += v * v;
    }
    ps[grp][ll] = s; pq[grp][ll] = q;
  }
  __syncthreads();
  if (tid < 64) {
    float S = ps[0][tid] + ps[1][tid] + ps[2][tid] + ps[3][tid];
    float Q = pq[0][tid] + pq[1][tid] + pq[2][tid] + pq[3][tid];
    float mu = S * (1.f / 128.f);
    float var = Q * (1.f / 128.f) - mu * mu;
    mu_s[tid] = mu;
    rs_s[tid] = rsqrtf(var + 1e-6f);
  }
  __syncthreads();
  for (int idx = tid; idx < CDIM * 64; idx += 256) {
    int c = idx >> 6, ll = idx & 63;
    float v = yt[ll][c];
    out[((size_t)(b * CDIM + c)) * LSEQ + l0 + ll] =
        v + nmw[c] * (v - mu_s[ll]) * rs_s[ll] + nmb[c];
  }
}

// depthwise causal conv4 + bias + silu; xz bf16 in, xc bf16 out
template <int MODE>
__global__ __launch_bounds__(256) void conv_kernel(
    const unsigned short* __restrict__ xz, const float* __restrict__ cw,
    const float* __restrict__ cb, unsigned short* __restrict__ xc) {
  __shared__ float xs[67][64];
  const int p0 = blockIdx.x * 64, d0 = blockIdx.y * 64, b = blockIdx.z;
  const int tid = threadIdx.x;
  for (int idx = tid; idx < 67 * 32; idx += 256) {
    int pp = idx >> 5, dd2 = idx & 31;
    int q = p0 + pp - 3;
    float v0 = 0.f, v1 = 0.f;
    if (q >= 0) {
      int l = lmap(q, MODE);
      unsigned uu = *(const unsigned*)&xz[((size_t)b * LSEQ + l) * ED + d0 + dd2 * 2];
      union { unsigned u; float f; } a, c;
      a.u = (uu & 0xFFFFu) << 16;
      c.u = uu & 0xFFFF0000u;
      v0 = a.f; v1 = c.f;
    }
    xs[pp][dd2 * 2] = v0;
    xs[pp][dd2 * 2 + 1] = v1;
  }
  __syncthreads();
  const int dd = tid & 63, pg = tid >> 6;
  const int d = d0 + dd;
  const float w0 = cw[d * 4 + 0], w1 = cw[d * 4 + 1];
  const float w2 = cw[d * 4 + 2], w3 = cw[d * 4 + 3];
  const float bias = cb[d];
  for (int pp = pg * 16; pp < pg * 16 + 16; ++pp) {
    float acc = bias + w0 * xs[pp][dd] + w1 * xs[pp + 1][dd] +
                w2 * xs[pp + 2][dd] + w3 * xs[pp + 3][dd];
    xc[((size_t)b * LSEQ + p0 + pp) * DI + d] = f2bf(fsilu(acc));
  }
}

// dt kernel: dtv[l][d] = softplus(xdbl[l,0:8] . dtw[d] + bias[d]) -> bf16.
// Tiny register footprint; runs once per dir before p1/p3.
__global__ __launch_bounds__(256) void dt_kernel(
    const float* __restrict__ xdbl, const float* __restrict__ dtw,
    const float* __restrict__ dtbias, unsigned short* __restrict__ dtv_buf) {
  __shared__ __align__(16) float Xl[CHL][8];
  const int c = blockIdx.x, b = blockIdx.y, d = threadIdx.x;
  const int p0 = c * CHL;
  for (int idx = d; idx < CHL * 8; idx += 256) {
    int pr = idx >> 3, r = idx & 7;
    Xl[pr][r] = xdbl[((size_t)b * LSEQ + p0 + pr) * 40 + r];
  }
  float dw[8];
  {
    const float4* Wv = (const float4*)(dtw + d * 8);
    float4 w0 = Wv[0], w1 = Wv[1];
    dw[0] = w0.x; dw[1] = w0.y; dw[2] = w0.z; dw[3] = w0.w;
    dw[4] = w1.x; dw[5] = w1.y; dw[6] = w1.z; dw[7] = w1.w;
  }
  const float dbias = dtbias[d];
  unsigned short* dtp = dtv_buf + ((size_t)b * LSEQ + p0) * DI + d;
  __syncthreads();
  for (int pr = 0; pr < CHL; ++pr) {
    const float4* Xr = (const float4*)Xl[pr];
    float4 x0 = Xr[0], x1 = Xr[1];
    float raw = dbias;
    raw = fmaf(dw[0], x0.x, raw); raw = fmaf(dw[1], x0.y, raw);
    raw = fmaf(dw[2], x0.z, raw); raw = fmaf(dw[3], x0.w, raw);
    raw = fmaf(dw[4], x1.x, raw); raw = fmaf(dw[5], x1.y, raw);
    raw = fmaf(dw[6], x1.z, raw); raw = fmaf(dw[7], x1.w, raw);
    *dtp = f2bf(fsoftplus(raw));
    dtp += DI;
  }
}

// phase 1 (state-split + cached dt): lane pair shares channel d; lane owns
// 8 states. Consumes dtv from dt_kernel (register use DECREASES vs round 16).
__global__ __launch_bounds__(256, 8) void scan_p1(
    const unsigned short* __restrict__ xc, const float* __restrict__ xdbl,
    const float* __restrict__ A2, const unsigned short* __restrict__ dtv_buf,
    unsigned short* __restrict__ hout, float* __restrict__ dts) {
  __shared__ __align__(16) float Xl[CHL][16];
  const int c = blockIdx.x, b = blockIdx.y;
  const int d = (blockIdx.z << 7) + (threadIdx.x >> 1);
  const int s = threadIdx.x & 1;
  const int p0 = c * CHL;
  for (int idx = threadIdx.x; idx < CHL * 16; idx += 256) {
    int pr = idx >> 4, r = idx & 15;
    Xl[pr][r] = xdbl[((size_t)b * LSEQ + p0 + pr) * 40 + 8 + r];
  }
  float a2[8], h[8];
  {
    const float4* A2v = (const float4*)(A2 + d * NST + s * 8);
    float4 t0 = A2v[0], t1 = A2v[1];
    a2[0] = t0.x; a2[1] = t0.y; a2[2] = t0.z; a2[3] = t0.w;
    a2[4] = t1.x; a2[5] = t1.y; a2[6] = t1.z; a2[7] = t1.w;
  }
#pragma unroll
  for (int n = 0; n < 8; ++n) h[n] = 0.f;
  float dtsum = 0.f;
  const unsigned short* up = xc + ((size_t)b * LSEQ + p0) * DI + d;
  const unsigned short* dtp = dtv_buf + ((size_t)b * LSEQ + p0) * DI + d;
  __syncthreads();
  for (int pr = 0; pr < CHL; ++pr) {
    const float u = bf2f(*up); up += DI;
    const float dtv = bf2f(*dtp); dtp += DI;
    const float dtu = dtv * u;
    dtsum += dtv;
    const float4* Xr = (const float4*)Xl[pr];
    float4 b0 = Xr[0 + 2 * s], b1 = Xr[1 + 2 * s];
    const float Bv[8] = {b0.x, b0.y, b0.z, b0.w, b1.x, b1.y, b1.z, b1.w};
#pragma unroll
    for (int n = 0; n < 8; ++n) {
      float a = FEXP2(dtv * a2[n]);
      h[n] = fmaf(h[n], a, dtu * Bv[n]);
    }
  }
  unsigned short* hb = hout + (((size_t)c * 4 + b) * DI + d) * NST + s * 8;
  uint4 pk;
  pk.x = ((unsigned)f2bf(h[1]) << 16) | f2bf(h[0]);
  pk.y = ((unsigned)f2bf(h[3]) << 16) | f2bf(h[2]);
  pk.z = ((unsigned)f2bf(h[5]) << 16) | f2bf(h[4]);
  pk.w = ((unsigned)f2bf(h[7]) << 16) | f2bf(h[6]);
  *(uint4*)hb = pk;
  if (s == 0) dts[((size_t)c * 4 + b) * DI + d] = dtsum;
}

// phase 2a: local scan within segments of SEG chunks (16 segments).
__global__ __launch_bounds__(256) void scan_p2a(
    unsigned short* __restrict__ hbuf, const float* __restrict__ dts,
    const float* __restrict__ A2, float* __restrict__ cumdts,
    float* __restrict__ segH, float* __restrict__ segdts) {
  const int s = blockIdx.x >> 4;
  const int rest = ((blockIdx.x & 15) << 8) + threadIdx.x;
  const int b = blockIdx.y;
  const int d = rest >> 4;
  const float a2 = A2[rest];
  const int c0 = s * SEG;
  float h = 0.f, cum = 0.f;
  float nh = bf2f(hbuf[((size_t)(c0 * 4 + b) << 12) + rest]);
  float nd = dts[(size_t)(c0 * 4 + b) * DI + d];
  for (int c = c0; c < c0 + SEG; ++c) {
    const float tmp = nh, dcur = nd;
    if (c + 1 < c0 + SEG) {
      nh = bf2f(hbuf[((size_t)((c + 1) * 4 + b) << 12) + rest]);
      nd = dts[(size_t)((c + 1) * 4 + b) * DI + d];
    }
    if ((rest & 15) == 0) cumdts[(size_t)(c * 4 + b) * DI + d] = cum;
    cum += dcur;
    hbuf[((size_t)(c * 4 + b) << 12) + rest] = f2bf(h);
    h = fmaf(FEXP2(dcur * a2), h, tmp);
  }
  segH[((size_t)(s * 4 + b) << 12) + rest] = h;
  if ((rest & 15) == 0) segdts[(size_t)(s * 4 + b) * DI + d] = cum;
}

// phase 2b: serial combine across the 16 segments (f32)
__global__ __launch_bounds__(256) void scan_p2b(
    const float* __restrict__ segH, const float* __restrict__ segdts,
    const float* __restrict__ A2, float* __restrict__ segcarry) {
  const int g = blockIdx.x * 256 + threadIdx.x;
  const int b = g >> 12;
  const int rest = g & 4095;
  const int d = rest >> 4;
  const float a2 = A2[rest];
  float carry = 0.f;
#pragma unroll
  for (int s = 0; s < 16; ++s) {
    segcarry[((size_t)(s * 4 + b) << 12) + rest] = carry;
    const float decay = FEXP2(segdts[(size_t)(s * 4 + b) * DI + d] * a2);
    carry = fmaf(decay, carry, segH[((size_t)(s * 4 + b) << 12) + rest]);
  }
}

// phase 3 (state-split + cached dt): verified numerically in round 17.
template <int MODE>
__global__ __launch_bounds__(256, 8) void scan_p3(
    const unsigned short* __restrict__ xc, const float* __restrict__ xdbl,
    const unsigned short* __restrict__ xz, const float* __restrict__ A2,
    const unsigned short* __restrict__ dtv_buf,
    const unsigned short* __restrict__ hinit, const float* __restrict__ cumdts,
    const float* __restrict__ segcarry, const float* __restrict__ Dp,
    unsigned short* __restrict__ ybuf) {
  __shared__ __align__(16) float Xl[CHL][32];
  const int c = blockIdx.x, b = blockIdx.y;
  const int d = (blockIdx.z << 7) + (threadIdx.x >> 1);
  const int s = threadIdx.x & 1;
  const int p0 = c * CHL;
  for (int idx = threadIdx.x; idx < CHL * 32; idx += 256) {
    int pr = idx >> 5, r = idx & 31;
    Xl[pr][r] = xdbl[((size_t)b * LSEQ + p0 + pr) * 40 + 8 + r];
  }
  float a2[8], h[8];
  {
    const float4* A2v = (const float4*)(A2 + d * NST + s * 8);
    float4 t0 = A2v[0], t1 = A2v[1];
    a2[0] = t0.x; a2[1] = t0.y; a2[2] = t0.z; a2[3] = t0.w;
    a2[4] = t1.x; a2[5] = t1.y; a2[6] = t1.z; a2[7] = t1.w;
    const uint4* Hv = (const uint4*)(hinit + (((size_t)c * 4 + b) * DI + d) * NST + s * 8);
    uint4 pa = Hv[0];
    const unsigned pw[4] = {pa.x, pa.y, pa.z, pa.w};
#pragma unroll
    for (int j = 0; j < 4; ++j) {
      union { unsigned u; float f; } lo, hi;
      lo.u = (pw[j] & 0xFFFFu) << 16;
      hi.u = pw[j] & 0xFFFF0000u;
      h[2 * j] = lo.f; h[2 * j + 1] = hi.f;
    }
    const float cum = cumdts[((size_t)c * 4 + b) * DI + d];
    const float4* SC = (const float4*)(segcarry +
        (((size_t)(c / SEG) * 4 + b) << 12) + d * NST + s * 8);
    float4 sc0 = SC[0], sc1 = SC[1];
    const float scv[8] = {sc0.x, sc0.y, sc0.z, sc0.w, sc1.x, sc1.y, sc1.z, sc1.w};
#pragma unroll
    for (int n = 0; n < 8; ++n)
      h[n] = fmaf(FEXP2(a2[n] * cum), scv[n], h[n]);
  }
  const float Dv = Dp[d];

  const unsigned short* up = xc + ((size_t)b * LSEQ + p0) * DI + d;
  const unsigned short* dtp = dtv_buf + ((size_t)b * LSEQ + p0) * DI + d;
  const unsigned short* zp;
  unsigned short* op;
  ptrdiff_t zstride, ostride;
  if (MODE == 0) {
    zp = xz + ((size_t)b * LSEQ + p0) * ED + DI + d;              zstride = ED;
    op = ybuf + ((size_t)b * LSEQ + p0) * DI + d;                 ostride = DI;
  } else if (MODE == 1) {
    zp = xz + ((size_t)b * LSEQ + (LSEQ - 1 - p0)) * ED + DI + d; zstride = -(ptrdiff_t)ED;
    op = ybuf + ((size_t)b * LSEQ + (LSEQ - 1 - p0)) * DI + d;    ostride = -(ptrdiff_t)DI;
  } else {
    zp = nullptr; zstride = 0;
    const int lo0 = (p0 % 576) * 16 + p0 / 576;
    op = ybuf + ((size_t)b * LSEQ + lo0) * DI + d;                ostride = 16 * DI;
  }
  __syncthreads();
  for (int pr = 0; pr < CHL; ++pr) {
    const float u = bf2f(*up); up += DI;
    const float dtv = bf2f(*dtp); dtp += DI;
    const float dtu = dtv * u;
    const float4* Xr = (const float4*)Xl[pr];
    float4 b0 = Xr[0 + 2 * s], b1 = Xr[1 + 2 * s];
    float4 c0 = Xr[4 + 2 * s], c1 = Xr[5 + 2 * s];
    const float Bv[8] = {b0.x, b0.y, b0.z, b0.w, b1.x, b1.y, b1.z, b1.w};
    const float Cv[8] = {c0.x, c0.y, c0.z, c0.w, c1.x, c1.y, c1.z, c1.w};
    float y = (s == 0) ? Dv * u : 0.f;
#pragma unroll
    for (int n = 0; n < 8; ++n) {
      float a = FEXP2(dtv * a2[n]);
      h[n] = fmaf(h[n], a, dtu * Bv[n]);
      y = fmaf(h[n], Cv[n], y);
    }
    y += __shfl_xor(y, 1);
    if (s == 0) {
      float z;
      if (MODE == 2) {
        const int p = p0 + pr;
        const int lz = (p & 15) * 576 + (p >> 4);
        z = bf2f(xz[((size_t)b * LSEQ + lz) * ED + DI + d]);
      } else {
        z = bf2f(*zp);
      }
      *op = f2bf(y * fsilu(z));
    }
    if (MODE != 2) zp += zstride;
    op += ostride;
  }
}

extern "C" void kernel_launch(void* const* d_in, const int* in_sizes, int n_in,
                              void* d_out, int out_size, void* d_ws, size_t ws_size,
                              hipStream_t stream) {
  (void)in_sizes; (void)n_in; (void)out_size;
  const float* x         = (const float*)d_in[0];
  const float* ln_w      = (const float*)d_in[1];
  const float* ln_b      = (const float*)d_in[2];
  const float* in_proj_w = (const float*)d_in[3];
  const float* out_projw = (const float*)d_in[4];
  const float* conv_w[3] = {(const float*)d_in[5],  (const float*)d_in[12], (const float*)d_in[19]};
  const float* conv_b[3] = {(const float*)d_in[6],  (const float*)d_in[13], (const float*)d_in[20]};
  const float* xproj[3]  = {(const float*)d_in[7],  (const float*)d_in[14], (const float*)d_in[21]};
  const float* dtw[3]    = {(const float*)d_in[8],  (const float*)d_in[15], (const float*)d_in[22]};
  const float* dtb[3]    = {(const float*)d_in[9],  (const float*)d_in[16], (const float*)d_in[23]};
  const float* alog[3]   = {(const float*)d_in[10], (const float*)d_in[17], (const float*)d_in[24]};
  const float* Dvec[3]   = {(const float*)d_in[11], (const float*)d_in[18], (const float*)d_in[25]};
  const float* nm_w      = (const float*)d_in[26];
  const float* nm_b      = (const float*)d_in[27];

  float* ws = (float*)d_ws;
  unsigned short* xn_us   = (unsigned short*)(ws);             // [0, 2359296)
  unsigned short* xz_us   = (unsigned short*)(ws + 2359296);   // [2359296, 11796480)
  unsigned short* xc_us   = (unsigned short*)(ws + 11796480);  // [11796480, 16515072)
  float* xdbl   = ws + 16515072;   // [16515072, 17989632)
  unsigned short* yf_us   = (unsigned short*)(ws + 17989632);  // [17989632, 22708224)
  unsigned short* yb_us   = (unsigned short*)(ws + 22708224);  // [22708224, 27426816)
  unsigned short* ys_us   = (unsigned short*)(ws + 27426816);  // [27426816, 32145408)
  float* A2     = ws + 32145408;   // [32145408, 32157696)
  unsigned short* wb = (unsigned short*)(ws + 32157696);       // [32157696, 32223232)
  unsigned short* hout_us = (unsigned short*)(ws + 32223232);  // [32223232, 36417536)
  float* dts      = ws + 36417536; // [36417536, 36941824)
  float* cumdts   = ws + 36941824; // [36941824, 37466112)
  float* segH     = ws + 37466112; // [37466112, 37728256)
  float* segdts   = ws + 37728256; // [37728256, 37744640)
  float* segcarry = ws + 37744640; // [37744640, 38006784)
  unsigned short* dtv_us = (unsigned short*)(ws + 38006784);   // [38006784, 42725376)
  if (ws_size < (size_t)42725376 * sizeof(float)) return;

  unsigned short* wb_in  = wb;
  unsigned short* wb_xp0 = wb + 65536;
  unsigned short* wb_xp1 = wb + 75776;
  unsigned short* wb_xp2 = wb + 86016;
  unsigned short* wb_out = wb + 96256;
  unsigned short* wb_xp[3] = {wb_xp0, wb_xp1, wb_xp2};
  unsigned short* ybuf[3] = {yf_us, yb_us, ys_us};

  a2_kernel<<<48, 256, 0, stream>>>(alog[0], alog[1], alog[2], A2);
  wcast_kernel<<<256, 256, 0, stream>>>(in_proj_w, wb_in, 65536);
  wcast_kernel<<<40, 256, 0, stream>>>(xproj[0], wb_xp0, 10240);
  wcast_kernel<<<40, 256, 0, stream>>>(xproj[1], wb_xp1, 10240);
  wcast_kernel<<<40, 256, 0, stream>>>(xproj[2], wb_xp2, 10240);
  wcast_kernel<<<128, 256, 0, stream>>>(out_projw, wb_out, 32768);

  ln_kernel<<<dim3(LSEQ / 64, 4), 256, 0, stream>>>(x, ln_w, ln_b, xn_us);
  gemm_mfma<true, true><<<dim3(576, 4), 256, 0, stream>>>(xn_us, wb_in, xz_us, 512, 128, 512);

  for (int dir = 0; dir < 3; ++dir) {
    if (dir == 0)
      conv_kernel<0><<<dim3(LSEQ / 64, 4, 4), 256, 0, stream>>>(xz_us, conv_w[0], conv_b[0], xc_us);
    else if (dir == 1)
      conv_kernel<1><<<dim3(LSEQ / 64, 4, 4), 256, 0, stream>>>(xz_us, conv_w[1], conv_b[1], xc_us);
    else
      conv_kernel<2><<<dim3(LSEQ / 64, 4, 4), 256, 0, stream>>>(xz_us, conv_w[2], conv_b[2], xc_us);

    gemm_mfma<true, false><<<dim3(576, 1), 256, 0, stream>>>(xc_us, wb_xp[dir], xdbl, 40, 256, 40);

    const float* A2d = A2 + dir * 4096;
    dt_kernel<<<dim3(NCH, 4), 256, 0, stream>>>(xdbl, dtw[dir], dtb[dir], dtv_us);

    dim3 sg(NCH, 4, 2);  // state-split: z picks channel half
    scan_p1<<<sg, 256, 0, stream>>>(xc_us, xdbl, A2d, dtv_us, hout_us, dts);
    scan_p2a<<<dim3(256, 4), 256, 0, stream>>>(hout_us, dts, A2d, cumdts, segH, segdts);
    scan_p2b<<<64, 256, 0, stream>>>(segH, segdts, A2d, segcarry);

    if (dir == 0)
      scan_p3<0><<<sg, 256, 0, stream>>>(xc_us, xdbl, xz_us, A2d, dtv_us,
                                         hout_us, cumdts, segcarry, Dvec[0], ybuf[0]);
    else if (dir == 1)
      scan_p3<1><<<sg, 256, 0, stream>>>(xc_us, xdbl, xz_us, A2d, dtv_us,
                                         hout_us, cumdts, segcarry, Dvec[1], ybuf[1]);
    else
      scan_p3<2><<<sg, 256, 0, stream>>>(xc_us, xdbl, xz_us, A2d, dtv_us,
                                         hout_us, cumdts, segcarry, Dvec[2], ybuf[2]);
  }
  gemm_out_final<<<576, 256, 0, stream>>>(yf_us, yb_us, ys_us, wb_out, x,
                                          nm_w, nm_b, (float*)d_out);
}

// Round 19
// 429.222 us; speedup vs baseline: 2.7362x; 1.4841x over previous
//
#include <hip/hip_runtime.h>

#define LSEQ 9216
#define CDIM 128
#define ED   512
#define DI   256
#define NST  16
#define NCH  512
#define CHL  18
#define SEG  32
#define LOG2E 1.44269504f
#define LN2  0.6931471805599453f

#if defined(__has_builtin)
#  if __has_builtin(__builtin_amdgcn_exp2f)
#    define FEXP2(x) __builtin_amdgcn_exp2f(x)
#  endif
#  if __has_builtin(__builtin_amdgcn_logf)
#    define FLOG2(x) __builtin_amdgcn_logf(x)
#  endif
#  if __has_builtin(__builtin_amdgcn_rcpf)
#    define FRCP(x) __builtin_amdgcn_rcpf(x)
#  endif
#endif
#ifndef FEXP2
#  define FEXP2(x) exp2f(x)
#endif
#ifndef FLOG2
#  define FLOG2(x) log2f(x)
#endif
#ifndef FRCP
#  define FRCP(x) (1.f / (x))
#endif

typedef __attribute__((ext_vector_type(8))) short short8v;
typedef __attribute__((ext_vector_type(4))) float float4v;

__device__ __forceinline__ float fsilu(float x) {
  return x * FRCP(1.f + FEXP2(-LOG2E * x));
}
__device__ __forceinline__ float fsoftplus(float x) {
  float sp = FLOG2(1.f + FEXP2(LOG2E * x)) * LN2;
  return (x > 20.f) ? x : sp;
}
__device__ __forceinline__ unsigned short f2bf(float f) {
  union { float f; unsigned u; } v; v.f = f;
  return (unsigned short)((v.u + 0x7FFFu + ((v.u >> 16) & 1u)) >> 16);
}
__device__ __forceinline__ float bf2f(unsigned short u) {
  union { unsigned u; float f; } v; v.u = ((unsigned)u) << 16;
  return v.f;
}
__device__ __forceinline__ int lmap(int p, int mode) {
  if (mode == 0) return p;
  if (mode == 1) return LSEQ - 1 - p;
  return (p & 15) * 576 + (p >> 4);
}

// Merged prep: A2 (3*4096) + all weight casts in one launch.
// Segments: [0,12288) A2 | [12288,77824) in_proj | [77824,88064) xp0 |
// [88064,98304) xp1 | [98304,108544) xp2 | [108544,141312) out_proj
__global__ __launch_bounds__(256) void prep_kernel(
    const float* __restrict__ Af, const float* __restrict__ Ab,
    const float* __restrict__ As, float* __restrict__ A2,
    const float* __restrict__ ipw, const float* __restrict__ xp0,
    const float* __restrict__ xp1, const float* __restrict__ xp2,
    const float* __restrict__ opw, unsigned short* __restrict__ wb_in,
    unsigned short* __restrict__ wb_xp0, unsigned short* __restrict__ wb_xp1,
    unsigned short* __restrict__ wb_xp2, unsigned short* __restrict__ wb_out) {
  int i = blockIdx.x * 256 + threadIdx.x;
  if (i < 12288) {
    int dir = i / 4096, j = i % 4096;
    const float* src = (dir == 0) ? Af : ((dir == 1) ? Ab : As);
    A2[i] = -expf(src[j]) * LOG2E;
    return;
  }
  i -= 12288;
  if (i < 65536) { wb_in[i] = f2bf(ipw[i]); return; }
  i -= 65536;
  if (i < 10240) { wb_xp0[i] = f2bf(xp0[i]); return; }
  i -= 10240;
  if (i < 10240) { wb_xp1[i] = f2bf(xp1[i]); return; }
  i -= 10240;
  if (i < 10240) { wb_xp2[i] = f2bf(xp2[i]); return; }
  i -= 10240;
  if (i < 32768) { wb_out[i] = f2bf(opw[i]); }
}

// LayerNorm over C at each (b,l): x (B,C,L) f32 -> xn (B,L,C) bf16
__global__ __launch_bounds__(256) void ln_kernel(
    const float* __restrict__ x, const float* __restrict__ w,
    const float* __restrict__ bb, unsigned short* __restrict__ xn) {
  __shared__ float xt[CDIM][65];
  __shared__ float ps[4][64], pq[4][64];
  __shared__ float mu_s[64], rs_s[64];
  const int b = blockIdx.y, l0 = blockIdx.x * 64, tid = threadIdx.x;
  for (int idx = tid; idx < CDIM * 64; idx += 256) {
    int c = idx >> 6, ll = idx & 63;
    xt[c][ll] = x[((size_t)(b * CDIM + c)) * LSEQ + l0 + ll];
  }
  __syncthreads();
  {
    int ll = tid & 63, grp = tid >> 6;
    float s = 0.f, q = 0.f;
    for (int c = grp * 32; c < grp * 32 + 32; ++c) {
      float v = xt[c][ll]; s += v; q += v * v;
    }
    ps[grp][ll] = s; pq[grp][ll] = q;
  }
  __syncthreads();
  if (tid < 64) {
    float S = ps[0][tid] + ps[1][tid] + ps[2][tid] + ps[3][tid];
    float Q = pq[0][tid] + pq[1][tid] + pq[2][tid] + pq[3][tid];
    float mu = S * (1.f / 128.f);
    float var = Q * (1.f / 128.f) - mu * mu;
    mu_s[tid] = mu;
    rs_s[tid] = rsqrtf(var + 1e-5f);
  }
  __syncthreads();
  for (int idx = tid; idx < 64 * CDIM; idx += 256) {
    int c = idx & 127, ll = idx >> 7;
    float v = (xt[c][ll] - mu_s[ll]) * rs_s[ll] * w[c] + bb[c];
    xn[((size_t)(b * LSEQ + l0 + ll)) * CDIM + c] = f2bf(v);
  }
}

// MFMA GEMM: Out[m,n] = sum_k A[m,k]*Wb[n,k].
template <bool A_BF16, bool OUT_BF16>
__global__ __launch_bounds__(256) void gemm_mfma(
    const void* __restrict__ Ap, const unsigned short* __restrict__ Wb,
    void* __restrict__ Outp, int N, int K, int ldo) {
  __shared__ __align__(16) unsigned short As[64][40];
  __shared__ __align__(16) unsigned short Bs[128][40];
  const int tid = threadIdx.x;
  const int lane = tid & 63, wid = tid >> 6;
  const int wr = wid >> 1, wc = wid & 1;
  const int m0 = blockIdx.x * 64, n0 = blockIdx.y * 128;
  float4v acc[2][4];
#pragma unroll
  for (int s = 0; s < 2; ++s)
#pragma unroll
    for (int t = 0; t < 4; ++t)
#pragma unroll
      for (int r = 0; r < 4; ++r) acc[s][t][r] = 0.f;

  const int srow = tid >> 2, sslot = tid & 3;
  for (int k0 = 0; k0 < K; k0 += 32) {
    if constexpr (A_BF16) {
      const unsigned short* A = (const unsigned short*)Ap;
      *(short8v*)&As[srow][sslot * 8] =
          *(const short8v*)&A[(size_t)(m0 + srow) * K + k0 + sslot * 8];
    } else {
      const float* A = (const float*)Ap;
      const float4* src = (const float4*)&A[(size_t)(m0 + srow) * K + k0 + sslot * 8];
      float4 f0 = src[0], f1 = src[1];
      short8v v;
      v[0] = (short)f2bf(f0.x); v[1] = (short)f2bf(f0.y);
      v[2] = (short)f2bf(f0.z); v[3] = (short)f2bf(f0.w);
      v[4] = (short)f2bf(f1.x); v[5] = (short)f2bf(f1.y);
      v[6] = (short)f2bf(f1.z); v[7] = (short)f2bf(f1.w);
      *(short8v*)&As[srow][sslot * 8] = v;
    }
#pragma unroll
    for (int i = 0; i < 2; ++i) {
      int row = i * 64 + srow;
      int n = n0 + row;
      short8v v;
      if (n < N) {
        v = *(const short8v*)&Wb[(size_t)n * K + k0 + sslot * 8];
      } else {
#pragma unroll
        for (int q = 0; q < 8; ++q) v[q] = 0;
      }
      *(short8v*)&Bs[row][sslot * 8] = v;
    }
    __syncthreads();
    const int kk = (lane >> 4) * 8;
    const int mr = wr * 32 + (lane & 15);
    const int nr = wc * 64 + (lane & 15);
    short8v a_frag[2], b_frag[4];
#pragma unroll
    for (int s = 0; s < 2; ++s)
      a_frag[s] = *(const short8v*)&As[mr + s * 16][kk];
#pragma unroll
    for (int t = 0; t < 4; ++t)
      b_frag[t] = *(const short8v*)&Bs[nr + t * 16][kk];
#pragma unroll
    for (int s = 0; s < 2; ++s)
#pragma unroll
      for (int t = 0; t < 4; ++t)
        acc[s][t] = __builtin_amdgcn_mfma_f32_16x16x32_bf16(
            a_frag[s], b_frag[t], acc[s][t], 0, 0, 0);
    __syncthreads();
  }
  const int rbase = (lane >> 4) * 4;
  const int cbase = lane & 15;
#pragma unroll
  for (int s = 0; s < 2; ++s)
#pragma unroll
    for (int t = 0; t < 4; ++t) {
      int n = n0 + wc * 64 + t * 16 + cbase;
      if (n < N) {
#pragma unroll
        for (int r = 0; r < 4; ++r) {
          int m = m0 + wr * 32 + s * 16 + rbase + r;
          if constexpr (OUT_BF16)
            ((unsigned short*)Outp)[(size_t)m * ldo + n] = f2bf(acc[s][t][r]);
          else
            ((float*)Outp)[(size_t)m * ldo + n] = acc[s][t][r];
        }
      }
    }
}

// Fused out_proj + residual + channel LayerNorm. (verified round-15)
__global__ __launch_bounds__(256) void gemm_out_final(
    const unsigned short* __restrict__ yf, const unsigned short* __restrict__ yb,
    const unsigned short* __restrict__ ys, const unsigned short* __restrict__ Wb,
    const float* __restrict__ x, const float* __restrict__ nmw,
    const float* __restrict__ nmb, float* __restrict__ out) {
  __shared__ __align__(16) unsigned short As[64][40];
  __shared__ __align__(16) unsigned short Bs[128][40];
  __shared__ float yt[64][129];
  __shared__ float ps[4][64], pq[4][64], mu_s[64], rs_s[64];
  const int tid = threadIdx.x;
  const int lane = tid & 63, wid = tid >> 6;
  const int wr = wid >> 1, wc = wid & 1;
  const int m0 = blockIdx.x * 64;
  const int b = blockIdx.x / 144, l0 = (blockIdx.x % 144) * 64;
  float4v acc[2][4];
#pragma unroll
  for (int s = 0; s < 2; ++s)
#pragma unroll
    for (int t = 0; t < 4; ++t)
#pragma unroll
      for (int r = 0; r < 4; ++r) acc[s][t][r] = 0.f;

  const int srow = tid >> 2, sslot = tid & 3;
  for (int k0 = 0; k0 < 256; k0 += 32) {
    {
      size_t base = (size_t)(m0 + srow) * DI + k0 + sslot * 8;
      short8v vf = *(const short8v*)&yf[base];
      short8v vb = *(const short8v*)&yb[base];
      short8v vs = *(const short8v*)&ys[base];
      short8v v;
#pragma unroll
      for (int q = 0; q < 8; ++q) {
        float f = bf2f((unsigned short)vf[q]) + bf2f((unsigned short)vb[q]) +
                  bf2f((unsigned short)vs[q]);
        v[q] = (short)f2bf(f);
      }
      *(short8v*)&As[srow][sslot * 8] = v;
    }
#pragma unroll
    for (int i = 0; i < 2; ++i) {
      int row = i * 64 + srow;
      *(short8v*)&Bs[row][sslot * 8] =
          *(const short8v*)&Wb[(size_t)row * 256 + k0 + sslot * 8];
    }
    __syncthreads();
    const int kk = (lane >> 4) * 8;
    const int mr = wr * 32 + (lane & 15);
    const int nr = wc * 64 + (lane & 15);
    short8v a_frag[2], b_frag[4];
#pragma unroll
    for (int s = 0; s < 2; ++s)
      a_frag[s] = *(const short8v*)&As[mr + s * 16][kk];
#pragma unroll
    for (int t = 0; t < 4; ++t)
      b_frag[t] = *(const short8v*)&Bs[nr + t * 16][kk];
#pragma unroll
    for (int s = 0; s < 2; ++s)
#pragma unroll
      for (int t = 0; t < 4; ++t)
        acc[s][t] = __builtin_amdgcn_mfma_f32_16x16x32_bf16(
            a_frag[s], b_frag[t], acc[s][t], 0, 0, 0);
    __syncthreads();
  }
  const int rbase = (lane >> 4) * 4;
  const int cbase = lane & 15;
#pragma unroll
  for (int s = 0; s < 2; ++s)
#pragma unroll
    for (int t = 0; t < 4; ++t) {
      int cc = wc * 64 + t * 16 + cbase;
#pragma unroll
      for (int r = 0; r < 4; ++r)
        yt[wr * 32 + s * 16 + rbase + r][cc] = acc[s][t][r];
    }
  __syncthreads();
  for (int idx = tid; idx < CDIM * 64; idx += 256) {
    int c = idx >> 6, ll = idx & 63;
    yt[ll][c] += x[((size_t)(b * CDIM + c)) * LSEQ + l0 + ll];
  }
  __syncthreads();
  {
    int ll = tid & 63, grp = tid >> 6;
    float s = 0.f, q = 0.f;
    for (int c = grp * 32; c < grp * 32 + 32; ++c) {
      float v = yt[ll][c]; s += v; q += v * v;
    }
    ps[grp][ll] = s; pq[grp][ll] = q;
  }
  __syncthreads();
  if (tid < 64) {
    float S = ps[0][tid] + ps[1][tid] + ps[2][tid] + ps[3][tid];
    float Q = pq[0][tid] + pq[1][tid] + pq[2][tid] + pq[3][tid];
    float mu = S * (1.f / 128.f);
    float var = Q * (1.f / 128.f) - mu * mu;
    mu_s[tid] = mu;
    rs_s[tid] = rsqrtf(var + 1e-6f);
  }
  __syncthreads();
  for (int idx = tid; idx < CDIM * 64; idx += 256) {
    int c = idx >> 6, ll = idx & 63;
    float v = yt[ll][c];
    out[((size_t)(b * CDIM + c)) * LSEQ + l0 + ll] =
        v + nmw[c] * (v - mu_s[ll]) * rs_s[ll] + nmb[c];
  }
}

// depthwise causal conv4 + bias + silu; xz bf16 in, xc bf16 out
template <int MODE>
__global__ __launch_bounds__(256) void conv_kernel(
    const unsigned short* __restrict__ xz, const float* __restrict__ cw,
    const float* __restrict__ cb, unsigned short* __restrict__ xc) {
  __shared__ float xs[67][64];
  const int p0 = blockIdx.x * 64, d0 = blockIdx.y * 64, b = blockIdx.z;
  const int tid = threadIdx.x;
  for (int idx = tid; idx < 67 * 32; idx += 256) {
    int pp = idx >> 5, dd2 = idx & 31;
    int q = p0 + pp - 3;
    float v0 = 0.f, v1 = 0.f;
    if (q >= 0) {
      int l = lmap(q, MODE);
      unsigned uu = *(const unsigned*)&xz[((size_t)b * LSEQ + l) * ED + d0 + dd2 * 2];
      union { unsigned u; float f; } a, c;
      a.u = (uu & 0xFFFFu) << 16;
      c.u = uu & 0xFFFF0000u;
      v0 = a.f; v1 = c.f;
    }
    xs[pp][dd2 * 2] = v0;
    xs[pp][dd2 * 2 + 1] = v1;
  }
  __syncthreads();
  const int dd = tid & 63, pg = tid >> 6;
  const int d = d0 + dd;
  const float w0 = cw[d * 4 + 0], w1 = cw[d * 4 + 1];
  const float w2 = cw[d * 4 + 2], w3 = cw[d * 4 + 3];
  const float bias = cb[d];
  for (int pp = pg * 16; pp < pg * 16 + 16; ++pp) {
    float acc = bias + w0 * xs[pp][dd] + w1 * xs[pp + 1][dd] +
                w2 * xs[pp + 2][dd] + w3 * xs[pp + 3][dd];
    xc[((size_t)b * LSEQ + p0 + pp) * DI + d] = f2bf(fsilu(acc));
  }
}

// phase 1 (state-split, round-16 verbatim — the ONLY proven spill-free
// configuration; do not modify): lane pair (2i,2i+1) shares channel d;
// each lane owns 8 states (s = tid&1).
__global__ __launch_bounds__(256, 8) void scan_p1(
    const unsigned short* __restrict__ xc, const float* __restrict__ xdbl,
    const float* __restrict__ A2, const float* __restrict__ dtw,
    const float* __restrict__ dtbias, unsigned short* __restrict__ hout,
    float* __restrict__ dts) {
  __shared__ __align__(16) float Xl[CHL][24];
  const int c = blockIdx.x, b = blockIdx.y;
  const int d = (blockIdx.z << 7) + (threadIdx.x >> 1);
  const int s = threadIdx.x & 1;
  const int p0 = c * CHL;
  for (int idx = threadIdx.x; idx < CHL * 24; idx += 256) {
    int pr = idx / 24, r = idx % 24;
    Xl[pr][r] = xdbl[((size_t)b * LSEQ + p0 + pr) * 40 + r];
  }
  float a2[8], h[8], dw[8];
  {
    const float4* A2v = (const float4*)(A2 + d * NST + s * 8);
    float4 t0 = A2v[0], t1 = A2v[1];
    a2[0] = t0.x; a2[1] = t0.y; a2[2] = t0.z; a2[3] = t0.w;
    a2[4] = t1.x; a2[5] = t1.y; a2[6] = t1.z; a2[7] = t1.w;
    const float4* Wv = (const float4*)(dtw + d * 8);
    float4 w0 = Wv[0], w1 = Wv[1];
    dw[0] = w0.x; dw[1] = w0.y; dw[2] = w0.z; dw[3] = w0.w;
    dw[4] = w1.x; dw[5] = w1.y; dw[6] = w1.z; dw[7] = w1.w;
  }
#pragma unroll
  for (int n = 0; n < 8; ++n) h[n] = 0.f;
  const float dbias = dtbias[d];
  float dtsum = 0.f;
  const unsigned short* up = xc + ((size_t)b * LSEQ + p0) * DI + d;
  __syncthreads();
  for (int pr = 0; pr < CHL; ++pr) {
    const float u = bf2f(*up); up += DI;
    const float4* Xr = (const float4*)Xl[pr];
    float4 x0 = Xr[0], x1 = Xr[1];
    float raw = dbias;
    raw = fmaf(dw[0], x0.x, raw); raw = fmaf(dw[1], x0.y, raw);
    raw = fmaf(dw[2], x0.z, raw); raw = fmaf(dw[3], x0.w, raw);
    raw = fmaf(dw[4], x1.x, raw); raw = fmaf(dw[5], x1.y, raw);
    raw = fmaf(dw[6], x1.z, raw); raw = fmaf(dw[7], x1.w, raw);
    const float dtv = fsoftplus(raw);
    const float dtu = dtv * u;
    dtsum += dtv;
    float4 b0 = Xr[2 + 2 * s], b1 = Xr[3 + 2 * s];
    const float Bv[8] = {b0.x, b0.y, b0.z, b0.w, b1.x, b1.y, b1.z, b1.w};
#pragma unroll
    for (int n = 0; n < 8; ++n) {
      float a = FEXP2(dtv * a2[n]);
      h[n] = fmaf(h[n], a, dtu * Bv[n]);
    }
  }
  unsigned short* hb = hout + (((size_t)c * 4 + b) * DI + d) * NST + s * 8;
  uint4 pk;
  pk.x = ((unsigned)f2bf(h[1]) << 16) | f2bf(h[0]);
  pk.y = ((unsigned)f2bf(h[3]) << 16) | f2bf(h[2]);
  pk.z = ((unsigned)f2bf(h[5]) << 16) | f2bf(h[4]);
  pk.w = ((unsigned)f2bf(h[7]) << 16) | f2bf(h[6]);
  *(uint4*)hb = pk;
  if (s == 0) dts[((size_t)c * 4 + b) * DI + d] = dtsum;
}

// phase 2a: local scan within segments of SEG chunks (16 segments).
__global__ __launch_bounds__(256) void scan_p2a(
    unsigned short* __restrict__ hbuf, const float* __restrict__ dts,
    const float* __restrict__ A2, float* __restrict__ cumdts,
    float* __restrict__ segH, float* __restrict__ segdts) {
  const int s = blockIdx.x >> 4;
  const int rest = ((blockIdx.x & 15) << 8) + threadIdx.x;
  const int b = blockIdx.y;
  const int d = rest >> 4;
  const float a2 = A2[rest];
  const int c0 = s * SEG;
  float h = 0.f, cum = 0.f;
  float nh = bf2f(hbuf[((size_t)(c0 * 4 + b) << 12) + rest]);
  float nd = dts[(size_t)(c0 * 4 + b) * DI + d];
  for (int c = c0; c < c0 + SEG; ++c) {
    const float tmp = nh, dcur = nd;
    if (c + 1 < c0 + SEG) {
      nh = bf2f(hbuf[((size_t)((c + 1) * 4 + b) << 12) + rest]);
      nd = dts[(size_t)((c + 1) * 4 + b) * DI + d];
    }
    if ((rest & 15) == 0) cumdts[(size_t)(c * 4 + b) * DI + d] = cum;
    cum += dcur;
    hbuf[((size_t)(c * 4 + b) << 12) + rest] = f2bf(h);
    h = fmaf(FEXP2(dcur * a2), h, tmp);
  }
  segH[((size_t)(s * 4 + b) << 12) + rest] = h;
  if ((rest & 15) == 0) segdts[(size_t)(s * 4 + b) * DI + d] = cum;
}

// phase 2b: serial combine across the 16 segments (f32)
__global__ __launch_bounds__(256) void scan_p2b(
    const float* __restrict__ segH, const float* __restrict__ segdts,
    const float* __restrict__ A2, float* __restrict__ segcarry) {
  const int g = blockIdx.x * 256 + threadIdx.x;
  const int b = g >> 12;
  const int rest = g & 4095;
  const int d = rest >> 4;
  const float a2 = A2[rest];
  float carry = 0.f;
#pragma unroll
  for (int s = 0; s < 16; ++s) {
    segcarry[((size_t)(s * 4 + b) << 12) + rest] = carry;
    const float decay = FEXP2(segdts[(size_t)(s * 4 + b) * DI + d] * a2);
    carry = fmaf(decay, carry, segH[((size_t)(s * 4 + b) << 12) + rest]);
  }
}

// phase 3 (state-split, round-16 verbatim): lane pair shares channel d;
// each lane owns 8 states; y reduced via shfl_xor(1); even lane stores.
template <int MODE>
__global__ __launch_bounds__(256, 8) void scan_p3(
    const unsigned short* __restrict__ xc, const float* __restrict__ xdbl,
    const unsigned short* __restrict__ xz, const float* __restrict__ A2,
    const float* __restrict__ dtw, const float* __restrict__ dtbias,
    const unsigned short* __restrict__ hinit, const float* __restrict__ cumdts,
    const float* __restrict__ segcarry, const float* __restrict__ Dp,
    unsigned short* __restrict__ ybuf) {
  __shared__ __align__(16) float Xl[CHL][40];
  const int c = blockIdx.x, b = blockIdx.y;
  const int d = (blockIdx.z << 7) + (threadIdx.x >> 1);
  const int s = threadIdx.x & 1;
  const int p0 = c * CHL;
  for (int idx = threadIdx.x; idx < CHL * 40; idx += 256) {
    int pr = idx / 40, r = idx % 40;
    Xl[pr][r] = xdbl[((size_t)b * LSEQ + p0 + pr) * 40 + r];
  }
  float a2[8], h[8], dw[8];
  {
    const float4* A2v = (const float4*)(A2 + d * NST + s * 8);
    float4 t0 = A2v[0], t1 = A2v[1];
    a2[0] = t0.x; a2[1] = t0.y; a2[2] = t0.z; a2[3] = t0.w;
    a2[4] = t1.x; a2[5] = t1.y; a2[6] = t1.z; a2[7] = t1.w;
    const uint4* Hv = (const uint4*)(hinit + (((size_t)c * 4 + b) * DI + d) * NST + s * 8);
    uint4 pa = Hv[0];
    const unsigned pw[4] = {pa.x, pa.y, pa.z, pa.w};
#pragma unroll
    for (int j = 0; j < 4; ++j) {
      union { unsigned u; float f; } lo, hi;
      lo.u = (pw[j] & 0xFFFFu) << 16;
      hi.u = pw[j] & 0xFFFF0000u;
      h[2 * j] = lo.f; h[2 * j + 1] = hi.f;
    }
    const float cum = cumdts[((size_t)c * 4 + b) * DI + d];
    const float4* SC = (const float4*)(segcarry +
        (((size_t)(c / SEG) * 4 + b) << 12) + d * NST + s * 8);
    float4 sc0 = SC[0], sc1 = SC[1];
    const float scv[8] = {sc0.x, sc0.y, sc0.z, sc0.w, sc1.x, sc1.y, sc1.z, sc1.w};
#pragma unroll
    for (int n = 0; n < 8; ++n)
      h[n] = fmaf(FEXP2(a2[n] * cum), scv[n], h[n]);
    const float4* Wv = (const float4*)(dtw + d * 8);
    float4 w0 = Wv[0], w1 = Wv[1];
    dw[0] = w0.x; dw[1] = w0.y; dw[2] = w0.z; dw[3] = w0.w;
    dw[4] = w1.x; dw[5] = w1.y; dw[6] = w1.z; dw[7] = w1.w;
  }
  const float dbias = dtbias[d];
  const float Dv = Dp[d];

  const unsigned short* up = xc + ((size_t)b * LSEQ + p0) * DI + d;
  const unsigned short* zp;
  unsigned short* op;
  ptrdiff_t zstride, ostride;
  if (MODE == 0) {
    zp = xz + ((size_t)b * LSEQ + p0) * ED + DI + d;              zstride = ED;
    op = ybuf + ((size_t)b * LSEQ + p0) * DI + d;                 ostride = DI;
  } else if (MODE == 1) {
    zp = xz + ((size_t)b * LSEQ + (LSEQ - 1 - p0)) * ED + DI + d; zstride = -(ptrdiff_t)ED;
    op = ybuf + ((size_t)b * LSEQ + (LSEQ - 1 - p0)) * DI + d;    ostride = -(ptrdiff_t)DI;
  } else {
    zp = nullptr; zstride = 0;
    const int lo0 = (p0 % 576) * 16 + p0 / 576;
    op = ybuf + ((size_t)b * LSEQ + lo0) * DI + d;                ostride = 16 * DI;
  }
  __syncthreads();
  for (int pr = 0; pr < CHL; ++pr) {
    const float u = bf2f(*up); up += DI;
    const float4* Xr = (const float4*)Xl[pr];
    float4 x0 = Xr[0], x1 = Xr[1];
    float raw = dbias;
    raw = fmaf(dw[0], x0.x, raw); raw = fmaf(dw[1], x0.y, raw);
    raw = fmaf(dw[2], x0.z, raw); raw = fmaf(dw[3], x0.w, raw);
    raw = fmaf(dw[4], x1.x, raw); raw = fmaf(dw[5], x1.y, raw);
    raw = fmaf(dw[6], x1.z, raw); raw = fmaf(dw[7], x1.w, raw);
    const float dtv = fsoftplus(raw);
    const float dtu = dtv * u;
    float4 b0 = Xr[2 + 2 * s], b1 = Xr[3 + 2 * s];
    float4 c0 = Xr[6 + 2 * s], c1 = Xr[7 + 2 * s];
    const float Bv[8] = {b0.x, b0.y, b0.z, b0.w, b1.x, b1.y, b1.z, b1.w};
    const float Cv[8] = {c0.x, c0.y, c0.z, c0.w, c1.x, c1.y, c1.z, c1.w};
    float y = (s == 0) ? Dv * u : 0.f;
#pragma unroll
    for (int n = 0; n < 8; ++n) {
      float a = FEXP2(dtv * a2[n]);
      h[n] = fmaf(h[n], a, dtu * Bv[n]);
      y = fmaf(h[n], Cv[n], y);
    }
    y += __shfl_xor(y, 1);
    if (s == 0) {
      float z;
      if (MODE == 2) {
        const int p = p0 + pr;
        const int lz = (p & 15) * 576 + (p >> 4);
        z = bf2f(xz[((size_t)b * LSEQ + lz) * ED + DI + d]);
      } else {
        z = bf2f(*zp);
      }
      *op = f2bf(y * fsilu(z));
    }
    if (MODE != 2) zp += zstride;
    op += ostride;
  }
}

extern "C" void kernel_launch(void* const* d_in, const int* in_sizes, int n_in,
                              void* d_out, int out_size, void* d_ws, size_t ws_size,
                              hipStream_t stream) {
  (void)in_sizes; (void)n_in; (void)out_size;
  const float* x         = (const float*)d_in[0];
  const float* ln_w      = (const float*)d_in[1];
  const float* ln_b      = (const float*)d_in[2];
  const float* in_proj_w = (const float*)d_in[3];
  const float* out_projw = (const float*)d_in[4];
  const float* conv_w[3] = {(const float*)d_in[5],  (const float*)d_in[12], (const float*)d_in[19]};
  const float* conv_b[3] = {(const float*)d_in[6],  (const float*)d_in[13], (const float*)d_in[20]};
  const float* xproj[3]  = {(const float*)d_in[7],  (const float*)d_in[14], (const float*)d_in[21]};
  const float* dtw[3]    = {(const float*)d_in[8],  (const float*)d_in[15], (const float*)d_in[22]};
  const float* dtb[3]    = {(const float*)d_in[9],  (const float*)d_in[16], (const float*)d_in[23]};
  const float* alog[3]   = {(const float*)d_in[10], (const float*)d_in[17], (const float*)d_in[24]};
  const float* Dvec[3]   = {(const float*)d_in[11], (const float*)d_in[18], (const float*)d_in[25]};
  const float* nm_w      = (const float*)d_in[26];
  const float* nm_b      = (const float*)d_in[27];

  float* ws = (float*)d_ws;
  unsigned short* xn_us   = (unsigned short*)(ws);             // [0, 2359296)
  unsigned short* xz_us   = (unsigned short*)(ws + 2359296);   // [2359296, 11796480)
  unsigned short* xc_us   = (unsigned short*)(ws + 11796480);  // [11796480, 16515072)
  float* xdbl   = ws + 16515072;   // [16515072, 17989632)
  unsigned short* yf_us   = (unsigned short*)(ws + 17989632);  // [17989632, 22708224)
  unsigned short* yb_us   = (unsigned short*)(ws + 22708224);  // [22708224, 27426816)
  unsigned short* ys_us   = (unsigned short*)(ws + 27426816);  // [27426816, 32145408)
  float* A2     = ws + 32145408;   // [32145408, 32157696)
  unsigned short* wb = (unsigned short*)(ws + 32157696);       // [32157696, 32223232)
  unsigned short* hout_us = (unsigned short*)(ws + 32223232);  // [32223232, 36417536)
  float* dts      = ws + 36417536; // [36417536, 36941824)
  float* cumdts   = ws + 36941824; // [36941824, 37466112)
  float* segH     = ws + 37466112; // [37466112, 37728256)
  float* segdts   = ws + 37728256; // [37728256, 37744640)
  float* segcarry = ws + 37744640; // [37744640, 38006784)
  if (ws_size < (size_t)38006784 * sizeof(float)) return;

  unsigned short* wb_in  = wb;
  unsigned short* wb_xp0 = wb + 65536;
  unsigned short* wb_xp1 = wb + 75776;
  unsigned short* wb_xp2 = wb + 86016;
  unsigned short* wb_out = wb + 96256;
  unsigned short* wb_xp[3] = {wb_xp0, wb_xp1, wb_xp2};
  unsigned short* ybuf[3] = {yf_us, yb_us, ys_us};

  // merged prep: A2 + all weight casts (141312 elements total)
  prep_kernel<<<(141312 + 255) / 256, 256, 0, stream>>>(
      alog[0], alog[1], alog[2], A2, in_proj_w, xproj[0], xproj[1], xproj[2],
      out_projw, wb_in, wb_xp0, wb_xp1, wb_xp2, wb_out);

  ln_kernel<<<dim3(LSEQ / 64, 4), 256, 0, stream>>>(x, ln_w, ln_b, xn_us);
  gemm_mfma<true, true><<<dim3(576, 4), 256, 0, stream>>>(xn_us, wb_in, xz_us, 512, 128, 512);

  for (int dir = 0; dir < 3; ++dir) {
    if (dir == 0)
      conv_kernel<0><<<dim3(LSEQ / 64, 4, 4), 256, 0, stream>>>(xz_us, conv_w[0], conv_b[0], xc_us);
    else if (dir == 1)
      conv_kernel<1><<<dim3(LSEQ / 64, 4, 4), 256, 0, stream>>>(xz_us, conv_w[1], conv_b[1], xc_us);
    else
      conv_kernel<2><<<dim3(LSEQ / 64, 4, 4), 256, 0, stream>>>(xz_us, conv_w[2], conv_b[2], xc_us);

    gemm_mfma<true, false><<<dim3(576, 1), 256, 0, stream>>>(xc_us, wb_xp[dir], xdbl, 40, 256, 40);

    const float* A2d = A2 + dir * 4096;
    dim3 sg(NCH, 4, 2);  // state-split: z picks channel half
    scan_p1<<<sg, 256, 0, stream>>>(xc_us, xdbl, A2d, dtw[dir], dtb[dir], hout_us, dts);
    scan_p2a<<<dim3(256, 4), 256, 0, stream>>>(hout_us, dts, A2d, cumdts, segH, segdts);
    scan_p2b<<<64, 256, 0, stream>>>(segH, segdts, A2d, segcarry);

    if (dir == 0)
      scan_p3<0><<<sg, 256, 0, stream>>>(xc_us, xdbl, xz_us, A2d, dtw[0], dtb[0],
                                         hout_us, cumdts, segcarry, Dvec[0], ybuf[0]);
    else if (dir == 1)
      scan_p3<1><<<sg, 256, 0, stream>>>(xc_us, xdbl, xz_us, A2d, dtw[1], dtb[1],
                                         hout_us, cumdts, segcarry, Dvec[1], ybuf[1]);
    else
      scan_p3<2><<<sg, 256, 0, stream>>>(xc_us, xdbl, xz_us, A2d, dtw[2], dtb[2],
                                         hout_us, cumdts, segcarry, Dvec[2], ybuf[2]);
  }
  gemm_out_final<<<576, 256, 0, stream>>>(yf_us, yb_us, ys_us, wb_out, x,
                                          nm_w, nm_b, (float*)d_out);
}